// Round 1
// 175.036 us; speedup vs baseline: 1.1407x; 1.1407x over previous
//
#include <hip/hip_runtime.h>
#include <hip/hip_bf16.h>

// Problem constants (fixed by the reference file)
#define LEAFN 1024
#define NN    2048            // nodes per batch incl. global node 0
#define BATCH 8
#define DD    128
#define ROWS  (BATCH*NN)      // 16384
#define AHS   384             // ah row stride: [agg(128) | hL0(128) | hL1(128)]
#define NB    256             // megakernel grid (1 block/CU)
#define NT    512             // threads per block (8 waves)

// ln(10000)/32
#define LOG1E4_OVER_32 0.28782313662425575f

// leafagg LDS layout: cache (<=201 rows * 272B), leaf-agg buffer, LN-red area
#define SLACK 9               // proven window coverage: drift <= 9 both sides
#define CSTRIDE 136           // ushorts per cache row (272 B, odd multiple of 16B)
#define AGGL_OFF 54672        // 201 * 272
#define RED_OFF  63376        // AGGL_OFF + 32*272 ; +1024 <= 65536

typedef __bf16 bf16x8 __attribute__((ext_vector_type(8)));
typedef float  floatx4 __attribute__((ext_vector_type(4)));
typedef float  floatx2 __attribute__((ext_vector_type(2)));

__device__ __forceinline__ float bf2f(unsigned short u) {
  return __uint_as_float(((unsigned)u) << 16);
}
__device__ __forceinline__ unsigned short f2bf(float f) {
  unsigned u = __float_as_uint(f);
  u += 0x7FFFu + ((u >> 16) & 1u);          // round-to-nearest-even
  return (unsigned short)(u >> 16);
}
__device__ __forceinline__ float gelu(float v) {
  return 0.5f * v * (1.0f + erff(v * 0.70710678118f));
}
__device__ __forceinline__ floatx2 bfpair(unsigned u) {
  floatx2 r;
  r[0] = __uint_as_float(u << 16);
  r[1] = __uint_as_float(u & 0xffff0000u);
  return r;
}

__device__ __forceinline__ float enc_val(int node, int d) {
  float hp, vp;
  if (node == 0) { hp = -0.5f; vp = -1.0f; }
  else {
    int v = 31 - __clz(node);
    hp = (float)(node - (1 << v));
    vp = (float)v;
  }
  float pos = (d < 64) ? hp : vp;
  int i = ((d < 64) ? d : (d - 64)) >> 1;
  float inv = __expf(-(float)i * LOG1E4_OVER_32);
  float ang = pos * inv;
  // |ang| <= 1023 rad = 163 rev, within v_sin range; error ~1e-5 << bf16 noise
  return (d & 1) ? __cosf(ang) : __sinf(ang);
}

// Cache window for block jb at level cd — MUST be identical in the eoff
// precompute and in ph_leafagg (single shared definition).
__device__ __forceinline__ void win_cd(int jb, int cd, int& lo_, int& wd_) {
  int g0 = 1024 + jb * 32, g1 = g0 + 31;
  int a0 = g0 >> (10 - cd), a1 = g1 >> (10 - cd);
  int l = a0 - SLACK, h = a1 + SLACK;
  int lvlo = 1 << cd, lvhi = (2 << cd) - 1;
  lo_ = l < lvlo ? lvlo : l;
  int hh = h > lvhi ? lvhi : h;
  int w = hh - lo_ + 1;
  wd_ = w < 0 ? 0 : w;
}

// ---------------------------------------------------------------------------
// Per-group barrier over 32 blocks. Group g = bid & 7.
__device__ __forceinline__ void gbarN(int* bar, int slot) {
  __syncthreads();
  if (threadIdx.x == 0) {
    int g = blockIdx.x & 7;
    int* base = bar + (slot * 8 + g) * 64;
    __threadfence();                           // release (L2 wb)
    if (__hip_atomic_fetch_add(base, 1, __ATOMIC_RELAXED,
                               __HIP_MEMORY_SCOPE_AGENT) == 31)
      __hip_atomic_store(base + 32, 1, __ATOMIC_RELAXED,
                         __HIP_MEMORY_SCOPE_AGENT);
    while (!__hip_atomic_load(base + 32, __ATOMIC_RELAXED,
                              __HIP_MEMORY_SCOPE_AGENT))
      __builtin_amdgcn_s_sleep(1);
    __threadfence();                           // acquire (L2 inv)
  }
  __syncthreads();
}

// ---------------------------------------------------------------------------
// Tree build + layer-0 LN/GELU + in-LDS subtree sums; stashes x0 of the 64
// internal-gemm tile rows into xci. Releases a lvl4-ready flag mid-phase so
// gb==16 can run ph_top during P0.
__device__ __forceinline__ void ph_tree(char* smemc, int b, int s,
                                        const float* __restrict__ elements,
                                        float* __restrict__ x,
                                        float* __restrict__ lvl4,
                                        unsigned short* __restrict__ ah,
                                        const float* __restrict__ gamma,
                                        const float* __restrict__ beta,
                                        float* __restrict__ sroot,
                                        float* xci, int* bar) {
  float* sm = (float*)smemc;                  // 127*128 floats = 63.5 KB
  int tid = threadIdx.x;
  const float4* src = (const float4*)(elements + (size_t)(b * LEAFN + s * 64) * DD);
  for (int i = tid; i < 2048; i += NT) {
    int f = i * 4;
    int j = f >> 7, d = f & 127;
    *(float4*)&sm[(63 + j) * DD + d] = src[i];
  }
  __syncthreads();
  for (int lv = 5; lv >= 0; --lv) {
    int nodes = 1 << lv;
    for (int idx = tid; idx < nodes * DD; idx += NT) {
      int k = nodes + (idx >> 7);
      int d = idx & 127;
      sm[(k - 1) * DD + d] = 0.5f * (sm[(2 * k - 1) * DD + d] + sm[(2 * k) * DD + d]);
    }
    __syncthreads();
  }
  if (tid < DD) lvl4[(b * 16 + s) * DD + tid] = sm[tid];
  __syncthreads();
  if (tid == 0) {                             // release lvl4-ready flag
    __threadfence();
    __hip_atomic_store(bar + 1536 + b * 64 + s * 4, 1, __ATOMIC_RELAXED,
                       __HIP_MEMORY_SCOPE_AGENT);
  }
  // x = feat + enc; keep in sm; write global x ONLY for leaf rows (k>=64)
  for (int idx = tid; idx < 127 * DD; idx += NT) {
    int k = (idx >> 7) + 1;
    int d = idx & 127;
    int lv = 31 - __clz(k);
    int g = ((16 + s) << lv) | (k - (1 << lv));
    float xv = sm[idx] + enc_val(g, d);
    if (k >= 64) x[((size_t)(b * NN + g)) * DD + d] = xv;
    sm[idx] = xv;
  }
  __syncthreads();
  // stash x0 for this block's internal gemm tiles (2 x 32 rows, dup t=63->k=1)
  {
    int wave = tid >> 6, lane = tid & 63;
    int mt = wave >> 2, nq = wave & 3;
    int m = lane & 15, q = lane >> 4;
#pragma unroll
    for (int c = 0; c < 2; ++c)
#pragma unroll
      for (int ci = 0; ci < 2; ++ci)
#pragma unroll
        for (int r = 0; r < 4; ++r) {
          int t = c * 32 + mt * 16 + q * 4 + r;
          int k = (t == 63) ? 1 : t + 1;
          int d = (nq * 2 + ci) * 16 + m;
          xci[c * 8 + ci * 4 + r] = sm[(k - 1) * DD + d];
        }
  }
  __syncthreads();
  // LN + GELU: h -> ah(+128) AND h overwrites sm (fp32). float4 LDS access.
  {
    int sub = tid & 7, dp = sub * 16;
    for (int rr = tid >> 3; rr < 127; rr += NT / 8) {
      float* rowp = &sm[rr * DD + dp];
      float4 q0 = *(float4*)rowp;
      float4 q1 = *(float4*)(rowp + 4);
      float4 q2 = *(float4*)(rowp + 8);
      float4 q3 = *(float4*)(rowp + 12);
      float v[16] = {q0.x, q0.y, q0.z, q0.w, q1.x, q1.y, q1.z, q1.w,
                     q2.x, q2.y, q2.z, q2.w, q3.x, q3.y, q3.z, q3.w};
      float s1 = 0.f, s2 = 0.f;
#pragma unroll
      for (int j = 0; j < 16; ++j) { s1 += v[j]; s2 += v[j] * v[j]; }
      s1 += __shfl_xor(s1, 1); s2 += __shfl_xor(s2, 1);
      s1 += __shfl_xor(s1, 2); s2 += __shfl_xor(s2, 2);
      s1 += __shfl_xor(s1, 4); s2 += __shfl_xor(s2, 4);
      float mu = s1 * (1.0f / 128.0f);
      float var = s2 * (1.0f / 128.0f) - mu * mu;
      float rinv = rsqrtf(var + 1e-5f);
      int k = rr + 1, lv = 31 - __clz(k);
      int g = ((16 + s) << lv) | (k - (1 << lv));
      __attribute__((aligned(16))) unsigned short o[16];
      float hv[16];
#pragma unroll
      for (int j = 0; j < 16; ++j) {
        hv[j] = gelu((v[j] - mu) * rinv * gamma[dp + j] + beta[dp + j]);
        o[j] = f2bf(hv[j]);
      }
      *(float4*)rowp        = make_float4(hv[0], hv[1], hv[2], hv[3]);
      *(float4*)(rowp + 4)  = make_float4(hv[4], hv[5], hv[6], hv[7]);
      *(float4*)(rowp + 8)  = make_float4(hv[8], hv[9], hv[10], hv[11]);
      *(float4*)(rowp + 12) = make_float4(hv[12], hv[13], hv[14], hv[15]);
      unsigned short* dst = &ah[(size_t)(b * NN + g) * AHS + 128 + dp];
      *(uint4*)&dst[0] = *(uint4*)&o[0];
      *(uint4*)&dst[8] = *(uint4*)&o[8];
    }
  }
  __syncthreads();
  // subtree-sum pyramid in LDS; agg (closed-form deg) -> ah(+0)
  for (int lv = 5; lv >= 0; --lv) {
    int nk = 1 << lv;
    float inv = 1.0f / (float)((1 << (7 - lv)) - 2);
    for (int idx = tid; idx < nk * DD; idx += NT) {
      int k = nk + (idx >> 7);
      int d = idx & 127;
      float S = sm[(2 * k - 1) * DD + d] + sm[(2 * k) * DD + d];
      if (lv < 5) S += sm[(4 * k - 1) * DD + d] + sm[(4 * k + 1) * DD + d];
      sm[(2 * k - 1) * DD + d] = S;
      int g = ((16 + s) << lv) | (k - nk);
      ah[(size_t)(b * NN + g) * AHS + d] = f2bf(S * inv);
    }
    __syncthreads();
  }
  if (tid < DD) sroot[(size_t)(b * 16 + s) * DD + tid] = sm[DD + tid];
}

// ---------------------------------------------------------------------------
// Top nodes 0..15: x0 into LDS xs (no global write), layer-0 h -> ah.
__device__ __forceinline__ void ph_top(char* smemc, int b,
                                       const float* __restrict__ lvl4,
                                       unsigned short* __restrict__ ah,
                                       const float* __restrict__ gamma,
                                       const float* __restrict__ beta) {
  float (*xs)[DD] = (float(*)[DD])smemc;      // 8 KB
  int tid = threadIdx.x;
  if (tid < 128) {
    int d = tid;
    float v[16];
    for (int j = 0; j < 16; ++j) v[j] = lvl4[(b * 16 + j) * DD + d];
    for (int j = 0; j < 8; ++j) v[j] = 0.5f * (v[2 * j] + v[2 * j + 1]);
    for (int j = 0; j < 8; ++j) xs[8 + j][d] = v[j] + enc_val(8 + j, d);
    for (int j = 0; j < 4; ++j) v[j] = 0.5f * (v[2 * j] + v[2 * j + 1]);
    for (int j = 0; j < 4; ++j) xs[4 + j][d] = v[j] + enc_val(4 + j, d);
    for (int j = 0; j < 2; ++j) v[j] = 0.5f * (v[2 * j] + v[2 * j + 1]);
    for (int j = 0; j < 2; ++j) xs[2 + j][d] = v[j] + enc_val(2 + j, d);
    v[0] = 0.5f * (v[0] + v[1]);
    xs[1][d] = v[0] + enc_val(1, d);
    xs[0][d] = -1.0f + enc_val(0, d);
  }
  __syncthreads();
  if (tid < 128) {
    int rr = tid >> 3, sub = tid & 7, dp = sub * 16;
    float w[16], s1 = 0.f, s2 = 0.f;
#pragma unroll
    for (int j = 0; j < 16; ++j) { w[j] = xs[rr][dp + j]; s1 += w[j]; s2 += w[j] * w[j]; }
    s1 += __shfl_xor(s1, 1); s2 += __shfl_xor(s2, 1);
    s1 += __shfl_xor(s1, 2); s2 += __shfl_xor(s2, 2);
    s1 += __shfl_xor(s1, 4); s2 += __shfl_xor(s2, 4);
    float mu = s1 * (1.0f / 128.0f);
    float var = s2 * (1.0f / 128.0f) - mu * mu;
    float rinv = rsqrtf(var + 1e-5f);
    __attribute__((aligned(16))) unsigned short o[16];
#pragma unroll
    for (int j = 0; j < 16; ++j)
      o[j] = f2bf(gelu((w[j] - mu) * rinv * gamma[dp + j] + beta[dp + j]));
    unsigned short* dst = &ah[(size_t)(b * NN + rr) * AHS + 128 + dp];
    *(uint4*)&dst[0] = *(uint4*)&o[0];
    *(uint4*)&dst[8] = *(uint4*)&o[8];
  }
  __syncthreads();
}

// ---------------------------------------------------------------------------
// Subtree sums for L1: reads h' from ah(+256), agg -> ah(+0), sroot.
__device__ __forceinline__ void ph_aggsub(char* smemc, int b, int s,
                                          unsigned short* ah,
                                          float* __restrict__ sroot) {
  floatx4 (*S)[32] = (floatx4(*)[32])smemc;   // 32 KB
  int tid = threadIdx.x;
  for (int idx = tid; idx < 32 * 32; idx += NT) {
    int k = 32 + (idx >> 5), q = idx & 31;
    int c = (16 + s) * 64 + (2 * k - 64);
    size_t a0 = (size_t)(b * NN + c) * AHS + 256 + q * 4;
    ushort4 u0 = *(const ushort4*)&ah[a0];
    ushort4 u1 = *(const ushort4*)&ah[a0 + AHS];
    floatx4 v;
    v[0] = bf2f(u0.x) + bf2f(u1.x);
    v[1] = bf2f(u0.y) + bf2f(u1.y);
    v[2] = bf2f(u0.z) + bf2f(u1.z);
    v[3] = bf2f(u0.w) + bf2f(u1.w);
    S[k][q] = v;
    int g = (16 + s) * 32 + (k - 32);
    int r = b * NN + g;
    ushort4 o;
    o.x = f2bf(v[0] * 0.5f); o.y = f2bf(v[1] * 0.5f);
    o.z = f2bf(v[2] * 0.5f); o.w = f2bf(v[3] * 0.5f);
    *(ushort4*)&ah[(size_t)r * AHS + q * 4] = o;
  }
  __syncthreads();
  for (int lv = 4; lv >= 0; --lv) {
    int nk = 1 << lv;
    float inv = 1.0f / (float)((1 << (7 - lv)) - 2);
    for (int idx = tid; idx < nk * 32; idx += NT) {
      int k = nk + (idx >> 5), q = idx & 31;
      int c = ((16 + s) << (lv + 1)) | (2 * k - 2 * nk);
      size_t a0 = (size_t)(b * NN + c) * AHS + 256 + q * 4;
      ushort4 u0 = *(const ushort4*)&ah[a0];
      ushort4 u1 = *(const ushort4*)&ah[a0 + AHS];
      floatx4 sc0 = S[2 * k][q], sc1 = S[2 * k + 1][q];
      floatx4 v;
      v[0] = bf2f(u0.x) + bf2f(u1.x) + sc0[0] + sc1[0];
      v[1] = bf2f(u0.y) + bf2f(u1.y) + sc0[1] + sc1[1];
      v[2] = bf2f(u0.z) + bf2f(u1.z) + sc0[2] + sc1[2];
      v[3] = bf2f(u0.w) + bf2f(u1.w) + sc0[3] + sc1[3];
      S[k][q] = v;
      int g = ((16 + s) << lv) | (k - nk);
      int r = b * NN + g;
      ushort4 o;
      o.x = f2bf(v[0] * inv); o.y = f2bf(v[1] * inv);
      o.z = f2bf(v[2] * inv); o.w = f2bf(v[3] * inv);
      *(ushort4*)&ah[(size_t)r * AHS + q * 4] = o;
    }
    __syncthreads();
  }
  for (int q = tid; q < 32; q += NT)
    ((floatx4*)sroot)[(size_t)(b * 16 + s) * 32 + q] = S[1][q];
}

// ---------------------------------------------------------------------------
// Leaf-row gather: per-level LDS window cache; edge offsets precomputed in
// eoff[] (u16 cache byte offsets, 0xFFFF = global fallback). Result agg goes
// to the aggl LDS buffer (consumed only by this block's ph_gemm32).
__device__ __forceinline__ void ph_leafagg(char* smemc, int b, int jb,
                                           const int* __restrict__ srcv,
                                           const int* __restrict__ s0a,
                                           const int* __restrict__ s1a,
                                           const unsigned short* __restrict__ eoff,
                                           unsigned short* ah, int hoff) {
  unsigned short* cache = (unsigned short*)smemc;  // <= 54672 B
  int tid = threadIdx.x;
  int lo[11], wd[11], off[11];
  int acc_off = 0;
#pragma unroll
  for (int cd = 10; cd >= 1; --cd) {
    win_cd(jb, cd, lo[cd], wd[cd]);
    off[cd] = acc_off;
    acc_off += wd[cd];
  }
#pragma unroll
  for (int cd = 10; cd >= 1; --cd) {
    int w = wd[cd];
    for (int t = tid; t < w * 16; t += NT) {
      int row = t >> 4, seg = t & 15;
      *(uint4*)&cache[(off[cd] + row) * CSTRIDE + seg * 8] =
          *(const uint4*)&ah[(size_t)(b * NN + lo[cd] + row) * AHS + hoff + seg * 8];
    }
  }
  __syncthreads();

  int leaf = tid >> 4, c = tid & 15;
  int r = b * NN + 1024 + jb * 32 + leaf;
  int e0 = s0a[r], e1 = s1a[r];
  int cb = c * 16;
  floatx2 a0 = {0.f, 0.f}, a1 = {0.f, 0.f}, a2 = {0.f, 0.f}, a3 = {0.f, 0.f};
  auto one = [&](int ei) {
    unsigned o = eoff[ei];
    uint4 u;
    if (o != 0xFFFFu)
      u = *(const uint4*)(smemc + o + cb);
    else {
      int g = srcv[ei] - b * NN;
      u = *(const uint4*)&ah[(size_t)(b * NN + g) * AHS + hoff + c * 8];
    }
    a0 += bfpair(u.x); a1 += bfpair(u.y); a2 += bfpair(u.z); a3 += bfpair(u.w);
  };
  int e = e0;
  for (; e + 4 <= e1; e += 4) {
    unsigned o0 = eoff[e], o1 = eoff[e + 1], o2 = eoff[e + 2], o3 = eoff[e + 3];
    if (!((((o0 + 1) | (o1 + 1) | (o2 + 1) | (o3 + 1)) >> 16))) {
      uint4 u0 = *(const uint4*)(smemc + o0 + cb);
      uint4 u1 = *(const uint4*)(smemc + o1 + cb);
      uint4 u2 = *(const uint4*)(smemc + o2 + cb);
      uint4 u3 = *(const uint4*)(smemc + o3 + cb);
      a0 += bfpair(u0.x); a1 += bfpair(u0.y); a2 += bfpair(u0.z); a3 += bfpair(u0.w);
      a0 += bfpair(u1.x); a1 += bfpair(u1.y); a2 += bfpair(u1.z); a3 += bfpair(u1.w);
      a0 += bfpair(u2.x); a1 += bfpair(u2.y); a2 += bfpair(u2.z); a3 += bfpair(u2.w);
      a0 += bfpair(u3.x); a1 += bfpair(u3.y); a2 += bfpair(u3.z); a3 += bfpair(u3.w);
    } else {
      one(e); one(e + 1); one(e + 2); one(e + 3);
    }
  }
  for (; e < e1; ++e) one(e);
  float inv = 1.0f / (float)max(e1 - e0, 1);
  unsigned short* aggl = (unsigned short*)(smemc + AGGL_OFF);
  __attribute__((aligned(16))) unsigned short o[8];
  o[0] = f2bf(a0[0] * inv); o[1] = f2bf(a0[1] * inv);
  o[2] = f2bf(a1[0] * inv); o[3] = f2bf(a1[1] * inv);
  o[4] = f2bf(a2[0] * inv); o[5] = f2bf(a2[1] * inv);
  o[6] = f2bf(a3[0] * inv); o[7] = f2bf(a3[1] * inv);
  *(uint4*)&aggl[leaf * CSTRIDE + c * 8] = *(uint4*)&o[0];
}

// ---------------------------------------------------------------------------
// Finish agg for nodes 0..15 (tid<128); h at +hoff, closed-form deg.
__device__ __forceinline__ void ph_topfin(int b,
                                          const float* __restrict__ sroot,
                                          unsigned short* ah, int hoff) {
  int d = threadIdx.x;
  float S16[16], h16[16], Sv[16];
#pragma unroll
  for (int j = 0; j < 16; ++j) S16[j] = sroot[(size_t)(b * 16 + j) * DD + d];
#pragma unroll
  for (int j = 0; j < 16; ++j)
    h16[j] = bf2f(ah[(size_t)(b * NN + 16 + j) * AHS + hoff + d]);
#pragma unroll
  for (int k = 8; k < 16; ++k)
    Sv[k] = h16[2 * k - 16] + h16[2 * k - 15] + S16[2 * k - 16] + S16[2 * k - 15];
#pragma unroll
  for (int k = 7; k >= 1; --k)
    Sv[k] = bf2f(ah[(size_t)(b * NN + 2 * k) * AHS + hoff + d]) +
            bf2f(ah[(size_t)(b * NN + 2 * k + 1) * AHS + hoff + d]) +
            Sv[2 * k] + Sv[2 * k + 1];
#pragma unroll
  for (int k = 1; k < 16; ++k) {
    int dv = 31 - __clz(k);
    float inv = 1.0f / (float)((1 << (11 - dv)) - 2);
    ah[(size_t)(b * NN + k) * AHS + d] = f2bf(Sv[k] * inv);
  }
  ah[(size_t)(b * NN) * AHS + d] = f2bf(0.0f);
}

// ---------------------------------------------------------------------------
// 32-row leaf GEMM tile (contiguous rows at rowbase). agg A-operand (kc<4)
// comes from the aggl LDS buffer written by this block's ph_leafagg.
__device__ __forceinline__ void ph_gemm32(char* redc, const unsigned short* aggl,
                                          int rowbase, unsigned short* ah,
                                          const unsigned short* __restrict__ wfl,
                                          const float* __restrict__ bn,
                                          float* __restrict__ x, int hoff_in,
                                          const float* __restrict__ gamma,
                                          const float* __restrict__ beta,
                                          float* xc, int first_layer) {
  int wave = threadIdx.x >> 6, lane = threadIdx.x & 63;
  int mt = wave >> 2, nq = wave & 3;
  int r0 = rowbase + mt * 16;
  int m = lane & 15, q = lane >> 4;
  const unsigned short* arow = ah + (size_t)(r0 + m) * AHS + q * 8;
  const bf16x8* B = (const bf16x8*)wfl + lane;
  floatx4 acc[2];
  acc[0] = (floatx4){0.f, 0.f, 0.f, 0.f};
  acc[1] = (floatx4){0.f, 0.f, 0.f, 0.f};
#pragma unroll
  for (int kc = 0; kc < 8; ++kc) {
    bf16x8 a0;
    if (kc < 4)
      a0 = *(const bf16x8*)&aggl[(mt * 16 + m) * CSTRIDE + kc * 32 + q * 8];
    else
      a0 = *(const bf16x8*)(arow + hoff_in + (kc - 4) * 32);
#pragma unroll
    for (int ci = 0; ci < 2; ++ci) {
      bf16x8 bb = B[(kc * 8 + nq * 2 + ci) * 64];
      acc[ci] = __builtin_amdgcn_mfma_f32_16x16x32_bf16(a0, bb, acc[ci], 0, 0, 0);
    }
  }
  if (first_layer) {
    float s1[4] = {0.f, 0.f, 0.f, 0.f}, s2[4] = {0.f, 0.f, 0.f, 0.f};
#pragma unroll
    for (int ci = 0; ci < 2; ++ci) {
      int col = (nq * 2 + ci) * 16 + m;
      float bias = bn[col];
#pragma unroll
      for (int r = 0; r < 4; ++r) {
        int row = r0 + q * 4 + r;
        float v = x[(size_t)row * DD + col] + acc[ci][r] + bias;
        xc[ci * 4 + r] = v;
        s1[r] += v; s2[r] += v * v;
      }
    }
#pragma unroll
    for (int r = 0; r < 4; ++r) {
      s1[r] += __shfl_xor(s1[r], 1); s2[r] += __shfl_xor(s2[r], 1);
      s1[r] += __shfl_xor(s1[r], 2); s2[r] += __shfl_xor(s2[r], 2);
      s1[r] += __shfl_xor(s1[r], 4); s2[r] += __shfl_xor(s2[r], 4);
      s1[r] += __shfl_xor(s1[r], 8); s2[r] += __shfl_xor(s2[r], 8);
    }
    float* red = (float*)redc;
    int rl = mt * 16 + q * 4;
    __syncthreads();
    if (m == 0) {
#pragma unroll
      for (int r = 0; r < 4; ++r) {
        red[(rl + r) * 4 + nq] = s1[r];
        red[128 + (rl + r) * 4 + nq] = s2[r];
      }
    }
    __syncthreads();
    float mu[4], rv[4];
#pragma unroll
    for (int r = 0; r < 4; ++r) {
      float t1 = red[(rl + r) * 4] + red[(rl + r) * 4 + 1] +
                 red[(rl + r) * 4 + 2] + red[(rl + r) * 4 + 3];
      float t2 = red[128 + (rl + r) * 4] + red[128 + (rl + r) * 4 + 1] +
                 red[128 + (rl + r) * 4 + 2] + red[128 + (rl + r) * 4 + 3];
      mu[r] = t1 * (1.0f / 128.0f);
      float var = t2 * (1.0f / 128.0f) - mu[r] * mu[r];
      rv[r] = rsqrtf(var + 1e-5f);
    }
#pragma unroll
    for (int ci = 0; ci < 2; ++ci) {
      int col = (nq * 2 + ci) * 16 + m;
      float gm = gamma[col], bt = beta[col];
#pragma unroll
      for (int r = 0; r < 4; ++r) {
        int row = r0 + q * 4 + r;
        float hh = gelu((xc[ci * 4 + r] - mu[r]) * rv[r] * gm + bt);
        ah[(size_t)row * AHS + 256 + col] = f2bf(hh);
      }
    }
  } else {
#pragma unroll
    for (int ci = 0; ci < 2; ++ci) {
      int col = (nq * 2 + ci) * 16 + m;
      float bias = bn[col];
#pragma unroll
      for (int r = 0; r < 4; ++r) {
        int row = r0 + q * 4 + r;
        x[(size_t)row * DD + col] = xc[ci * 4 + r] + acc[ci][r] + bias;
      }
    }
  }
}

// ---------------------------------------------------------------------------
// 32-row internal GEMM tile with SCATTERED rows: t = tbase+local, k = (t==63)?
// 1 : t+1, row = subtree-sb heap node. x0 preloaded in xc (no x read).
__device__ __forceinline__ void ph_gemm32s(char* redc, int b, int sb, int tbase,
                                           unsigned short* ah,
                                           const unsigned short* __restrict__ wfl,
                                           const float* __restrict__ bn,
                                           float* __restrict__ x, int hoff_in,
                                           const float* __restrict__ gamma,
                                           const float* __restrict__ beta,
                                           float* xc, int first_layer) {
  int wave = threadIdx.x >> 6, lane = threadIdx.x & 63;
  int mt = wave >> 2, nq = wave & 3;
  int m = lane & 15, q = lane >> 4;
  int tA = tbase + mt * 16 + m;
  int kA = (tA == 63) ? 1 : tA + 1;
  int lvA = 31 - __clz(kA);
  int rowA = b * NN + (((16 + sb) << lvA) | (kA - (1 << lvA)));
  int rowO[4];
#pragma unroll
  for (int r = 0; r < 4; ++r) {
    int t = tbase + mt * 16 + q * 4 + r;
    int k = (t == 63) ? 1 : t + 1;
    int lv = 31 - __clz(k);
    rowO[r] = b * NN + (((16 + sb) << lv) | (k - (1 << lv)));
  }
  const unsigned short* arow = ah + (size_t)rowA * AHS + q * 8;
  const bf16x8* B = (const bf16x8*)wfl + lane;
  floatx4 acc[2];
  acc[0] = (floatx4){0.f, 0.f, 0.f, 0.f};
  acc[1] = (floatx4){0.f, 0.f, 0.f, 0.f};
#pragma unroll
  for (int kc = 0; kc < 8; ++kc) {
    int koff = (kc < 4) ? kc * 32 : hoff_in + (kc - 4) * 32;
    bf16x8 a0 = *(const bf16x8*)(arow + koff);
#pragma unroll
    for (int ci = 0; ci < 2; ++ci) {
      bf16x8 bb = B[(kc * 8 + nq * 2 + ci) * 64];
      acc[ci] = __builtin_amdgcn_mfma_f32_16x16x32_bf16(a0, bb, acc[ci], 0, 0, 0);
    }
  }
  if (first_layer) {
    float s1[4] = {0.f, 0.f, 0.f, 0.f}, s2[4] = {0.f, 0.f, 0.f, 0.f};
#pragma unroll
    for (int ci = 0; ci < 2; ++ci) {
      int col = (nq * 2 + ci) * 16 + m;
      float bias = bn[col];
#pragma unroll
      for (int r = 0; r < 4; ++r) {
        float v = xc[ci * 4 + r] + acc[ci][r] + bias;
        xc[ci * 4 + r] = v;
        s1[r] += v; s2[r] += v * v;
      }
    }
#pragma unroll
    for (int r = 0; r < 4; ++r) {
      s1[r] += __shfl_xor(s1[r], 1); s2[r] += __shfl_xor(s2[r], 1);
      s1[r] += __shfl_xor(s1[r], 2); s2[r] += __shfl_xor(s2[r], 2);
      s1[r] += __shfl_xor(s1[r], 4); s2[r] += __shfl_xor(s2[r], 4);
      s1[r] += __shfl_xor(s1[r], 8); s2[r] += __shfl_xor(s2[r], 8);
    }
    float* red = (float*)redc;
    int rl = mt * 16 + q * 4;
    __syncthreads();
    if (m == 0) {
#pragma unroll
      for (int r = 0; r < 4; ++r) {
        red[(rl + r) * 4 + nq] = s1[r];
        red[128 + (rl + r) * 4 + nq] = s2[r];
      }
    }
    __syncthreads();
    float mu[4], rv[4];
#pragma unroll
    for (int r = 0; r < 4; ++r) {
      float t1 = red[(rl + r) * 4] + red[(rl + r) * 4 + 1] +
                 red[(rl + r) * 4 + 2] + red[(rl + r) * 4 + 3];
      float t2 = red[128 + (rl + r) * 4] + red[128 + (rl + r) * 4 + 1] +
                 red[128 + (rl + r) * 4 + 2] + red[128 + (rl + r) * 4 + 3];
      mu[r] = t1 * (1.0f / 128.0f);
      float var = t2 * (1.0f / 128.0f) - mu[r] * mu[r];
      rv[r] = rsqrtf(var + 1e-5f);
    }
#pragma unroll
    for (int ci = 0; ci < 2; ++ci) {
      int col = (nq * 2 + ci) * 16 + m;
      float gm = gamma[col], bt = beta[col];
#pragma unroll
      for (int r = 0; r < 4; ++r) {
        float hh = gelu((xc[ci * 4 + r] - mu[r]) * rv[r] * gm + bt);
        ah[(size_t)rowO[r] * AHS + 256 + col] = f2bf(hh);
      }
    }
  } else {
#pragma unroll
    for (int ci = 0; ci < 2; ++ci) {
      int col = (nq * 2 + ci) * 16 + m;
      float bias = bn[col];
#pragma unroll
      for (int r = 0; r < 4; ++r)
        x[(size_t)rowO[r] * DD + col] = xc[ci * 4 + r] + acc[ci][r] + bias;
    }
  }
}

// ---------------------------------------------------------------------------
// 16-row top GEMM tile (rows 0..15 of batch b). 8 waves = 8 col-tiles.
__device__ __forceinline__ void ph_gemm16t(char* redc, int b,
                                           unsigned short* ah,
                                           const unsigned short* __restrict__ wfl,
                                           const float* __restrict__ bn,
                                           float* __restrict__ x, int hoff_in,
                                           const float* __restrict__ gamma,
                                           const float* __restrict__ beta,
                                           float* xc, int first_layer) {
  int ct = threadIdx.x >> 6, lane = threadIdx.x & 63;
  int m = lane & 15, q = lane >> 4;
  const unsigned short* arow = ah + (size_t)(b * NN + m) * AHS + q * 8;
  const bf16x8* B = (const bf16x8*)wfl + lane;
  floatx4 acc = (floatx4){0.f, 0.f, 0.f, 0.f};
#pragma unroll
  for (int kc = 0; kc < 8; ++kc) {
    int koff = (kc < 4) ? kc * 32 : hoff_in + (kc - 4) * 32;
    bf16x8 a0 = *(const bf16x8*)(arow + koff);
    bf16x8 bb = B[(kc * 8 + ct) * 64];
    acc = __builtin_amdgcn_mfma_f32_16x16x32_bf16(a0, bb, acc, 0, 0, 0);
  }
  int col = ct * 16 + m;
  float bias = bn[col];
  if (first_layer) {
    float s1[4], s2[4];
#pragma unroll
    for (int r = 0; r < 4; ++r) {
      float v = xc[r] + acc[r] + bias;
      xc[r] = v; s1[r] = v; s2[r] = v * v;
    }
#pragma unroll
    for (int r = 0; r < 4; ++r) {
      s1[r] += __shfl_xor(s1[r], 1); s2[r] += __shfl_xor(s2[r], 1);
      s1[r] += __shfl_xor(s1[r], 2); s2[r] += __shfl_xor(s2[r], 2);
      s1[r] += __shfl_xor(s1[r], 4); s2[r] += __shfl_xor(s2[r], 4);
      s1[r] += __shfl_xor(s1[r], 8); s2[r] += __shfl_xor(s2[r], 8);
    }
    float* red = (float*)redc;
    __syncthreads();
    if (m == 0) {
#pragma unroll
      for (int r = 0; r < 4; ++r) {
        red[(q * 4 + r) * 8 + ct] = s1[r];
        red[128 + (q * 4 + r) * 8 + ct] = s2[r];
      }
    }
    __syncthreads();
#pragma unroll
    for (int r = 0; r < 4; ++r) {
      float t1 = 0.f, t2 = 0.f;
#pragma unroll
      for (int j = 0; j < 8; ++j) {
        t1 += red[(q * 4 + r) * 8 + j];
        t2 += red[128 + (q * 4 + r) * 8 + j];
      }
      float mu = t1 * (1.0f / 128.0f);
      float var = t2 * (1.0f / 128.0f) - mu * mu;
      float rv = rsqrtf(var + 1e-5f);
      float hh = gelu((xc[r] - mu) * rv * gamma[col] + beta[col]);
      ah[(size_t)(b * NN + q * 4 + r) * AHS + 256 + col] = f2bf(hh);
    }
  } else {
#pragma unroll
    for (int r = 0; r < 4; ++r)
      x[(size_t)(b * NN + q * 4 + r) * DD + col] = xc[r] + acc[r] + bias;
  }
}

// ---------------------------------------------------------------------------
// Megakernel: 8 XCD-affine groups x 32 blocks (group = bid&7 = batch).
// gb 0-15: tree blocks. gb 16-23: CSR + eoff precompute (gb==16 also owns the
// top-node chain, gated on lvl4-ready flags). gb 24-31: weight repack.
__global__ __launch_bounds__(NT, 1) void k_mega(
    const float* __restrict__ elements, const float* __restrict__ ln_gamma,
    const float* __restrict__ ln_beta, const float* __restrict__ w_nei,
    const float* __restrict__ b_nei, const float* __restrict__ w_root,
    const int* __restrict__ srcv, const int* __restrict__ dstv, int E,
    float* __restrict__ x, int* s0a, int* s1a, float* lvl4, float* sroot,
    unsigned short* wf, unsigned short* ah, unsigned short* eoff, int* bar) {
  __shared__ __align__(16) char smem[65536];
  int bid = blockIdx.x, tid = threadIdx.x;
  int b = bid & 7, gb = bid >> 3;    // XCD-affine: batch = bid % 8
  int Eb = E >> 3;
  unsigned short* wfg = wf + (size_t)b * 65536;
  float xcl[8], xci[16], xct[4];

  // ---- P0 ----
  if (gb < 16) {
    ph_tree(smem, b, gb, elements, x, lvl4, ah, ln_gamma, ln_beta, sroot, xci, bar);
  } else if (gb < 24) {
    int base = b * Eb;
    for (int i = base + (gb - 16) * NT + tid; i < base + Eb; i += 8 * NT) {
      int dv = dstv[i];
      if (i == 0 || dstv[i - 1] != dv) s0a[dv] = i;
      if (i == base + Eb - 1 || dstv[i + 1] != dv) s1a[dv] = i + 1;
    }
    // precompute per-edge resolved cache byte-offsets for leaf-dst edges
    for (int i = base + (gb - 16) * NT + tid; i < base + Eb; i += 8 * NT) {
      int dl = dstv[i] - b * NN - 1024;
      unsigned short ov = 0xFFFFu;
      if (dl >= 0) {
        int jb2 = dl >> 5;
        int g = srcv[i] - b * NN;
        int lv = 31 - __clz(g);
        int acc2 = 0;
#pragma unroll
        for (int cd = 10; cd >= 1; --cd) {
          int lo_, wd_;
          win_cd(jb2, cd, lo_, wd_);
          if (cd == lv) {
            int idx = g - lo_;
            if ((unsigned)idx < (unsigned)wd_)
              ov = (unsigned short)((acc2 + idx) * (2 * CSTRIDE));
          }
          acc2 += wd_;
        }
      }
      eoff[i] = ov;
    }
    if (gb == 16) {
      // wait for all 16 lvl4 slices of this batch, then top-node x0 + h
      if (tid < 16) {
        while (!__hip_atomic_load(bar + 1536 + b * 64 + tid * 4, __ATOMIC_RELAXED,
                                  __HIP_MEMORY_SCOPE_AGENT))
          __builtin_amdgcn_s_sleep(1);
        __threadfence();
      }
      __syncthreads();
      ph_top(smem, b, lvl4, ah, ln_gamma, ln_beta);  // xs in LDS, h0..15 -> ah
      {                                              // stash xct from xs
        int wv = tid >> 6, ln = tid & 63, m_ = ln & 15, q_ = ln >> 4;
        float (*xs)[DD] = (float(*)[DD])smem;
#pragma unroll
        for (int r = 0; r < 4; ++r) xct[r] = xs[q_ * 4 + r][wv * 16 + m_];
      }
    }
  } else {
    int gi = (gb - 24) * NT + tid;   // 0..4095 frag units
    int lane = gi & 63, ct = (gi >> 6) & 7, kc = gi >> 9;
    int n = ct * 16 + (lane & 15);
    int k = kc * 32 + (lane >> 4) * 8;
    int kk = k & 127;
#pragma unroll
    for (int l = 0; l < 2; ++l) {
      const float* w = (k < 128) ? (w_nei + (size_t)l * DD * DD)
                                 : (w_root + (size_t)l * DD * DD);
      unsigned short* o = wfg + (size_t)l * 32768 + (size_t)gi * 8;
#pragma unroll
      for (int j = 0; j < 8; ++j) o[j] = f2bf(w[(size_t)(kk + j) * DD + n]);
    }
  }
  gbarN(bar, 0);

  // ---- P1 (layer 0) ----
  if (gb == 16) {
    if (tid < 128) ph_topfin(b, sroot, ah, 128);
    __syncthreads();
    ph_gemm16t(smem + RED_OFF, b, ah, wfg, b_nei, x, 128,
               ln_gamma + DD, ln_beta + DD, xct, 1);
    __syncthreads();
  }
  ph_leafagg(smem, b, gb, srcv, s0a, s1a, eoff, ah, 128);
  __syncthreads();
  ph_gemm32(smem + RED_OFF, (const unsigned short*)(smem + AGGL_OFF),
            b * NN + 1024 + gb * 32, ah, wfg, b_nei, x, 128,
            ln_gamma + DD, ln_beta + DD, xcl, 1);
  if (gb < 16) {
    ph_gemm32s(smem + RED_OFF, b, gb, 0, ah, wfg, b_nei, x, 128,
               ln_gamma + DD, ln_beta + DD, xci, 1);
    ph_gemm32s(smem + RED_OFF, b, gb, 32, ah, wfg, b_nei, x, 128,
               ln_gamma + DD, ln_beta + DD, xci + 8, 1);
  }
  gbarN(bar, 1);

  // ---- P2 (layer 1): no group barrier; gb==16 waits on 16 sroot flags ----
  if (gb < 16) {
    ph_aggsub(smem, b, gb, ah, sroot);
    __syncthreads();
    if (tid == 0) {
      __threadfence();
      __hip_atomic_store(bar + 1024 + b * 64 + gb * 4, 1, __ATOMIC_RELAXED,
                         __HIP_MEMORY_SCOPE_AGENT);
    }
  }
  ph_leafagg(smem, b, gb, srcv, s0a, s1a, eoff, ah, 256);
  __syncthreads();
  ph_gemm32(smem + RED_OFF, (const unsigned short*)(smem + AGGL_OFF),
            b * NN + 1024 + gb * 32, ah, wfg + 32768, b_nei + DD,
            x, 256, ln_gamma, ln_beta, xcl, 0);
  if (gb < 16) {
    ph_gemm32s(smem + RED_OFF, b, gb, 0, ah, wfg + 32768, b_nei + DD, x, 256,
               ln_gamma, ln_beta, xci, 0);
    ph_gemm32s(smem + RED_OFF, b, gb, 32, ah, wfg + 32768, b_nei + DD, x, 256,
               ln_gamma, ln_beta, xci + 8, 0);
  } else if (gb == 16) {
    if (tid < 16) {
      while (!__hip_atomic_load(bar + 1024 + b * 64 + tid * 4, __ATOMIC_RELAXED,
                                __HIP_MEMORY_SCOPE_AGENT))
        __builtin_amdgcn_s_sleep(1);
      __threadfence();
    }
    __syncthreads();
    if (tid < 128) ph_topfin(b, sroot, ah, 256);
    __syncthreads();
    ph_gemm16t(smem + RED_OFF, b, ah, wfg + 32768, b_nei + DD, x, 256,
               ln_gamma, ln_beta, xct, 0);
  }
}

// ---------------------------------------------------------------------------
extern "C" void kernel_launch(void* const* d_in, const int* in_sizes, int n_in,
                              void* d_out, int out_size, void* d_ws, size_t ws_size,
                              hipStream_t stream) {
  const float* elements = (const float*)d_in[0];
  const float* ln_gamma = (const float*)d_in[1];
  const float* ln_beta  = (const float*)d_in[2];
  const float* w_nei    = (const float*)d_in[3];
  const float* b_nei    = (const float*)d_in[4];
  const float* w_root   = (const float*)d_in[5];
  const int*   edge     = (const int*)d_in[6];
  int E = in_sizes[6] / 2;
  const int* srcv = edge;
  const int* dstv = edge + E;
  float* x = (float*)d_out;

  char* ws = (char*)d_ws;
  int*            bar   = (int*)ws;                         // 8 KB used
  int*            s0    = (int*)(ws + 65536);               // 64 KB
  int*            s1    = (int*)(ws + 131072);              // 64 KB
  float*          lvl4  = (float*)(ws + 196608);            // 64 KB
  float*          sroot = (float*)(ws + 262144);            // 64 KB
  unsigned short* wf    = (unsigned short*)(ws + 327680);   // 1 MB (8 copies)
  unsigned short* ah    = (unsigned short*)(ws + 327680 + 1048576);  // 12.6 MB
  unsigned short* eoff  = (unsigned short*)(ws + 327680 + 1048576 + 12582912); // 2E B

  hipMemsetAsync(bar, 0, 8192, stream);
  k_mega<<<dim3(NB), dim3(NT), 0, stream>>>(
      elements, ln_gamma, ln_beta, w_nei, b_nei, w_root,
      srcv, dstv, E, x, s0, s1, lvl4, sroot, wf, ah, eoff, bar);
}

// Round 2
// 168.981 us; speedup vs baseline: 1.1816x; 1.0358x over previous
//
#include <hip/hip_runtime.h>
#include <hip/hip_bf16.h>

// Problem constants (fixed by the reference file)
#define LEAFN 1024
#define NN    2048            // nodes per batch incl. global node 0
#define BATCH 8
#define DD    128
#define ROWS  (BATCH*NN)      // 16384
#define AHS   384             // ah row stride: [agg(128) | hL0(128) | hL1(128)]
#define NB    256             // megakernel grid (1 block/CU)
#define NT    1024            // threads per block (16 waves; gemm uses first 8)

// ln(10000)/32
#define LOG1E4_OVER_32 0.28782313662425575f

// leafagg LDS layout: cache (<=201 rows * 272B), leaf-agg buffer, LN-red area
#define SLACK 9               // proven window coverage: drift <= 9 both sides
#define CSTRIDE 136           // ushorts per cache row (272 B, odd multiple of 16B)
#define AGGL_OFF 54672        // 201 * 272
#define RED_OFF  63376        // AGGL_OFF + 32*272 ; +1024 <= 65536

typedef __bf16 bf16x8 __attribute__((ext_vector_type(8)));
typedef float  floatx4 __attribute__((ext_vector_type(4)));
typedef float  floatx2 __attribute__((ext_vector_type(2)));

__device__ __forceinline__ float bf2f(unsigned short u) {
  return __uint_as_float(((unsigned)u) << 16);
}
__device__ __forceinline__ unsigned short f2bf(float f) {
  unsigned u = __float_as_uint(f);
  u += 0x7FFFu + ((u >> 16) & 1u);          // round-to-nearest-even
  return (unsigned short)(u >> 16);
}
__device__ __forceinline__ float gelu(float v) {
  return 0.5f * v * (1.0f + erff(v * 0.70710678118f));
}
__device__ __forceinline__ floatx2 bfpair(unsigned u) {
  floatx2 r;
  r[0] = __uint_as_float(u << 16);
  r[1] = __uint_as_float(u & 0xffff0000u);
  return r;
}

__device__ __forceinline__ float enc_val(int node, int d) {
  float hp, vp;
  if (node == 0) { hp = -0.5f; vp = -1.0f; }
  else {
    int v = 31 - __clz(node);
    hp = (float)(node - (1 << v));
    vp = (float)v;
  }
  float pos = (d < 64) ? hp : vp;
  int i = ((d < 64) ? d : (d - 64)) >> 1;
  float inv = __expf(-(float)i * LOG1E4_OVER_32);
  float ang = pos * inv;
  // |ang| <= 1023 rad = 163 rev, within v_sin range; error ~1e-5 << bf16 noise
  return (d & 1) ? __cosf(ang) : __sinf(ang);
}

// Cache window for block jb at level cd — MUST be identical in the eoff
// precompute and in ph_leafagg (single shared definition).
__device__ __forceinline__ void win_cd(int jb, int cd, int& lo_, int& wd_) {
  int g0 = 1024 + jb * 32, g1 = g0 + 31;
  int a0 = g0 >> (10 - cd), a1 = g1 >> (10 - cd);
  int l = a0 - SLACK, h = a1 + SLACK;
  int lvlo = 1 << cd, lvhi = (2 << cd) - 1;
  lo_ = l < lvlo ? lvlo : l;
  int hh = h > lvhi ? lvhi : h;
  int w = hh - lo_ + 1;
  wd_ = w < 0 ? 0 : w;
}

// ---------------------------------------------------------------------------
// Per-group barrier over 32 blocks. Group g = bid & 7.
__device__ __forceinline__ void gbarN(int* bar, int slot) {
  __syncthreads();
  if (threadIdx.x == 0) {
    int g = blockIdx.x & 7;
    int* base = bar + (slot * 8 + g) * 64;
    __threadfence();                           // release (L2 wb)
    if (__hip_atomic_fetch_add(base, 1, __ATOMIC_RELAXED,
                               __HIP_MEMORY_SCOPE_AGENT) == 31)
      __hip_atomic_store(base + 32, 1, __ATOMIC_RELAXED,
                         __HIP_MEMORY_SCOPE_AGENT);
    while (!__hip_atomic_load(base + 32, __ATOMIC_RELAXED,
                              __HIP_MEMORY_SCOPE_AGENT))
      __builtin_amdgcn_s_sleep(1);
    __threadfence();                           // acquire (L2 inv)
  }
  __syncthreads();
}

// ---------------------------------------------------------------------------
// Tree build + layer-0 LN/GELU + in-LDS subtree sums; stashes x0 of the 64
// internal-gemm tile rows into xci (waves 0-7 only). Releases a lvl4-ready
// flag mid-phase so gb==16 can run ph_top during P0.
__device__ __forceinline__ void ph_tree(char* smemc, int b, int s,
                                        const float* __restrict__ elements,
                                        float* __restrict__ x,
                                        float* __restrict__ lvl4,
                                        unsigned short* __restrict__ ah,
                                        const float* __restrict__ gamma,
                                        const float* __restrict__ beta,
                                        float* __restrict__ sroot,
                                        float* xci, int* bar) {
  float* sm = (float*)smemc;                  // 127*128 floats = 63.5 KB
  int tid = threadIdx.x;
  const float4* src = (const float4*)(elements + (size_t)(b * LEAFN + s * 64) * DD);
  for (int i = tid; i < 2048; i += NT) {
    int f = i * 4;
    int j = f >> 7, d = f & 127;
    *(float4*)&sm[(63 + j) * DD + d] = src[i];
  }
  __syncthreads();
  for (int lv = 5; lv >= 0; --lv) {
    int nodes = 1 << lv;
    for (int idx = tid; idx < nodes * DD; idx += NT) {
      int k = nodes + (idx >> 7);
      int d = idx & 127;
      sm[(k - 1) * DD + d] = 0.5f * (sm[(2 * k - 1) * DD + d] + sm[(2 * k) * DD + d]);
    }
    __syncthreads();
  }
  if (tid < DD) lvl4[(b * 16 + s) * DD + tid] = sm[tid];
  __syncthreads();
  if (tid == 0) {                             // release lvl4-ready flag
    __threadfence();
    __hip_atomic_store(bar + 1536 + b * 64 + s * 4, 1, __ATOMIC_RELAXED,
                       __HIP_MEMORY_SCOPE_AGENT);
  }
  // x = feat + enc; keep in sm; write global x ONLY for leaf rows (k>=64)
  for (int idx = tid; idx < 127 * DD; idx += NT) {
    int k = (idx >> 7) + 1;
    int d = idx & 127;
    int lv = 31 - __clz(k);
    int g = ((16 + s) << lv) | (k - (1 << lv));
    float xv = sm[idx] + enc_val(g, d);
    if (k >= 64) x[((size_t)(b * NN + g)) * DD + d] = xv;
    sm[idx] = xv;
  }
  __syncthreads();
  // stash x0 for this block's internal gemm tiles (2 x 32 rows, dup t=63->k=1)
  {
    int wave = tid >> 6, lane = tid & 63;
    if (wave < 8) {
      int mt = wave >> 2, nq = wave & 3;
      int m = lane & 15, q = lane >> 4;
#pragma unroll
      for (int c = 0; c < 2; ++c)
#pragma unroll
        for (int ci = 0; ci < 2; ++ci)
#pragma unroll
          for (int r = 0; r < 4; ++r) {
            int t = c * 32 + mt * 16 + q * 4 + r;
            int k = (t == 63) ? 1 : t + 1;
            int d = (nq * 2 + ci) * 16 + m;
            xci[c * 8 + ci * 4 + r] = sm[(k - 1) * DD + d];
          }
    }
  }
  __syncthreads();
  // LN + GELU: h -> ah(+128) AND h overwrites sm (fp32). float4 LDS access.
  {
    int sub = tid & 7, dp = sub * 16;
    for (int rr = tid >> 3; rr < 127; rr += NT / 8) {
      float* rowp = &sm[rr * DD + dp];
      float4 q0 = *(float4*)rowp;
      float4 q1 = *(float4*)(rowp + 4);
      float4 q2 = *(float4*)(rowp + 8);
      float4 q3 = *(float4*)(rowp + 12);
      float v[16] = {q0.x, q0.y, q0.z, q0.w, q1.x, q1.y, q1.z, q1.w,
                     q2.x, q2.y, q2.z, q2.w, q3.x, q3.y, q3.z, q3.w};
      float s1 = 0.f, s2 = 0.f;
#pragma unroll
      for (int j = 0; j < 16; ++j) { s1 += v[j]; s2 += v[j] * v[j]; }
      s1 += __shfl_xor(s1, 1); s2 += __shfl_xor(s2, 1);
      s1 += __shfl_xor(s1, 2); s2 += __shfl_xor(s2, 2);
      s1 += __shfl_xor(s1, 4); s2 += __shfl_xor(s2, 4);
      float mu = s1 * (1.0f / 128.0f);
      float var = s2 * (1.0f / 128.0f) - mu * mu;
      float rinv = rsqrtf(var + 1e-5f);
      int k = rr + 1, lv = 31 - __clz(k);
      int g = ((16 + s) << lv) | (k - (1 << lv));
      __attribute__((aligned(16))) unsigned short o[16];
      float hv[16];
#pragma unroll
      for (int j = 0; j < 16; ++j) {
        hv[j] = gelu((v[j] - mu) * rinv * gamma[dp + j] + beta[dp + j]);
        o[j] = f2bf(hv[j]);
      }
      *(float4*)rowp        = make_float4(hv[0], hv[1], hv[2], hv[3]);
      *(float4*)(rowp + 4)  = make_float4(hv[4], hv[5], hv[6], hv[7]);
      *(float4*)(rowp + 8)  = make_float4(hv[8], hv[9], hv[10], hv[11]);
      *(float4*)(rowp + 12) = make_float4(hv[12], hv[13], hv[14], hv[15]);
      unsigned short* dst = &ah[(size_t)(b * NN + g) * AHS + 128 + dp];
      *(uint4*)&dst[0] = *(uint4*)&o[0];
      *(uint4*)&dst[8] = *(uint4*)&o[8];
    }
  }
  __syncthreads();
  // subtree-sum pyramid in LDS; agg (closed-form deg) -> ah(+0)
  for (int lv = 5; lv >= 0; --lv) {
    int nk = 1 << lv;
    float inv = 1.0f / (float)((1 << (7 - lv)) - 2);
    for (int idx = tid; idx < nk * DD; idx += NT) {
      int k = nk + (idx >> 7);
      int d = idx & 127;
      float S = sm[(2 * k - 1) * DD + d] + sm[(2 * k) * DD + d];
      if (lv < 5) S += sm[(4 * k - 1) * DD + d] + sm[(4 * k + 1) * DD + d];
      sm[(2 * k - 1) * DD + d] = S;
      int g = ((16 + s) << lv) | (k - nk);
      ah[(size_t)(b * NN + g) * AHS + d] = f2bf(S * inv);
    }
    __syncthreads();
  }
  if (tid < DD) sroot[(size_t)(b * 16 + s) * DD + tid] = sm[DD + tid];
}

// ---------------------------------------------------------------------------
// Top nodes 0..15: x0 into LDS xs (no global write), layer-0 h -> ah.
__device__ __forceinline__ void ph_top(char* smemc, int b,
                                       const float* __restrict__ lvl4,
                                       unsigned short* __restrict__ ah,
                                       const float* __restrict__ gamma,
                                       const float* __restrict__ beta) {
  float (*xs)[DD] = (float(*)[DD])smemc;      // 8 KB
  int tid = threadIdx.x;
  if (tid < 128) {
    int d = tid;
    float v[16];
    for (int j = 0; j < 16; ++j) v[j] = lvl4[(b * 16 + j) * DD + d];
    for (int j = 0; j < 8; ++j) v[j] = 0.5f * (v[2 * j] + v[2 * j + 1]);
    for (int j = 0; j < 8; ++j) xs[8 + j][d] = v[j] + enc_val(8 + j, d);
    for (int j = 0; j < 4; ++j) v[j] = 0.5f * (v[2 * j] + v[2 * j + 1]);
    for (int j = 0; j < 4; ++j) xs[4 + j][d] = v[j] + enc_val(4 + j, d);
    for (int j = 0; j < 2; ++j) v[j] = 0.5f * (v[2 * j] + v[2 * j + 1]);
    for (int j = 0; j < 2; ++j) xs[2 + j][d] = v[j] + enc_val(2 + j, d);
    v[0] = 0.5f * (v[0] + v[1]);
    xs[1][d] = v[0] + enc_val(1, d);
    xs[0][d] = -1.0f + enc_val(0, d);
  }
  __syncthreads();
  if (tid < 128) {
    int rr = tid >> 3, sub = tid & 7, dp = sub * 16;
    float w[16], s1 = 0.f, s2 = 0.f;
#pragma unroll
    for (int j = 0; j < 16; ++j) { w[j] = xs[rr][dp + j]; s1 += w[j]; s2 += w[j] * w[j]; }
    s1 += __shfl_xor(s1, 1); s2 += __shfl_xor(s2, 1);
    s1 += __shfl_xor(s1, 2); s2 += __shfl_xor(s2, 2);
    s1 += __shfl_xor(s1, 4); s2 += __shfl_xor(s2, 4);
    float mu = s1 * (1.0f / 128.0f);
    float var = s2 * (1.0f / 128.0f) - mu * mu;
    float rinv = rsqrtf(var + 1e-5f);
    __attribute__((aligned(16))) unsigned short o[16];
#pragma unroll
    for (int j = 0; j < 16; ++j)
      o[j] = f2bf(gelu((w[j] - mu) * rinv * gamma[dp + j] + beta[dp + j]));
    unsigned short* dst = &ah[(size_t)(b * NN + rr) * AHS + 128 + dp];
    *(uint4*)&dst[0] = *(uint4*)&o[0];
    *(uint4*)&dst[8] = *(uint4*)&o[8];
  }
  __syncthreads();
}

// ---------------------------------------------------------------------------
// Subtree sums for L1: reads h' from ah(+256), agg -> ah(+0), sroot.
__device__ __forceinline__ void ph_aggsub(char* smemc, int b, int s,
                                          unsigned short* ah,
                                          float* __restrict__ sroot) {
  floatx4 (*S)[32] = (floatx4(*)[32])smemc;   // 32 KB
  int tid = threadIdx.x;
  for (int idx = tid; idx < 32 * 32; idx += NT) {
    int k = 32 + (idx >> 5), q = idx & 31;
    int c = (16 + s) * 64 + (2 * k - 64);
    size_t a0 = (size_t)(b * NN + c) * AHS + 256 + q * 4;
    ushort4 u0 = *(const ushort4*)&ah[a0];
    ushort4 u1 = *(const ushort4*)&ah[a0 + AHS];
    floatx4 v;
    v[0] = bf2f(u0.x) + bf2f(u1.x);
    v[1] = bf2f(u0.y) + bf2f(u1.y);
    v[2] = bf2f(u0.z) + bf2f(u1.z);
    v[3] = bf2f(u0.w) + bf2f(u1.w);
    S[k][q] = v;
    int g = (16 + s) * 32 + (k - 32);
    int r = b * NN + g;
    ushort4 o;
    o.x = f2bf(v[0] * 0.5f); o.y = f2bf(v[1] * 0.5f);
    o.z = f2bf(v[2] * 0.5f); o.w = f2bf(v[3] * 0.5f);
    *(ushort4*)&ah[(size_t)r * AHS + q * 4] = o;
  }
  __syncthreads();
  for (int lv = 4; lv >= 0; --lv) {
    int nk = 1 << lv;
    float inv = 1.0f / (float)((1 << (7 - lv)) - 2);
    for (int idx = tid; idx < nk * 32; idx += NT) {
      int k = nk + (idx >> 5), q = idx & 31;
      int c = ((16 + s) << (lv + 1)) | (2 * k - 2 * nk);
      size_t a0 = (size_t)(b * NN + c) * AHS + 256 + q * 4;
      ushort4 u0 = *(const ushort4*)&ah[a0];
      ushort4 u1 = *(const ushort4*)&ah[a0 + AHS];
      floatx4 sc0 = S[2 * k][q], sc1 = S[2 * k + 1][q];
      floatx4 v;
      v[0] = bf2f(u0.x) + bf2f(u1.x) + sc0[0] + sc1[0];
      v[1] = bf2f(u0.y) + bf2f(u1.y) + sc0[1] + sc1[1];
      v[2] = bf2f(u0.z) + bf2f(u1.z) + sc0[2] + sc1[2];
      v[3] = bf2f(u0.w) + bf2f(u1.w) + sc0[3] + sc1[3];
      S[k][q] = v;
      int g = ((16 + s) << lv) | (k - nk);
      int r = b * NN + g;
      ushort4 o;
      o.x = f2bf(v[0] * inv); o.y = f2bf(v[1] * inv);
      o.z = f2bf(v[2] * inv); o.w = f2bf(v[3] * inv);
      *(ushort4*)&ah[(size_t)r * AHS + q * 4] = o;
    }
    __syncthreads();
  }
  for (int q = tid; q < 32; q += NT)
    ((floatx4*)sroot)[(size_t)(b * 16 + s) * 32 + q] = S[1][q];
}

// ---------------------------------------------------------------------------
// Leaf-row gather: per-level LDS window cache; edge offsets precomputed in
// eoff[] (u16 cache byte offsets, 0xFFFF = global fallback). 32 threads per
// leaf: bit4 of tid selects which HALF of the edge range this thread walks;
// halves combined via shfl_xor(16). Result agg -> aggl LDS buffer.
__device__ __forceinline__ void ph_leafagg(char* smemc, int b, int jb,
                                           const int* __restrict__ srcv,
                                           const int* __restrict__ s0a,
                                           const int* __restrict__ s1a,
                                           const unsigned short* __restrict__ eoff,
                                           unsigned short* ah, int hoff) {
  unsigned short* cache = (unsigned short*)smemc;  // <= 54672 B
  int tid = threadIdx.x;
  int lo[11], wd[11], off[11];
  int acc_off = 0;
#pragma unroll
  for (int cd = 10; cd >= 1; --cd) {
    win_cd(jb, cd, lo[cd], wd[cd]);
    off[cd] = acc_off;
    acc_off += wd[cd];
  }
#pragma unroll
  for (int cd = 10; cd >= 1; --cd) {
    int w = wd[cd];
    for (int t = tid; t < w * 16; t += NT) {
      int row = t >> 4, seg = t & 15;
      *(uint4*)&cache[(off[cd] + row) * CSTRIDE + seg * 8] =
          *(const uint4*)&ah[(size_t)(b * NN + lo[cd] + row) * AHS + hoff + seg * 8];
    }
  }
  __syncthreads();

  int leaf = tid >> 5, half = (tid >> 4) & 1, c = tid & 15;
  int r = b * NN + 1024 + jb * 32 + leaf;
  int e0 = s0a[r], e1 = s1a[r];
  int n = e1 - e0;
  int mid = e0 + (n >> 1);
  int ebeg = half ? mid : e0;
  int eend = half ? e1 : mid;
  int cb = c * 16;
  floatx2 a0 = {0.f, 0.f}, a1 = {0.f, 0.f}, a2 = {0.f, 0.f}, a3 = {0.f, 0.f};
  auto one = [&](int ei) {
    unsigned o = eoff[ei];
    uint4 u;
    if (o != 0xFFFFu)
      u = *(const uint4*)(smemc + o + cb);
    else {
      int g = srcv[ei] - b * NN;
      u = *(const uint4*)&ah[(size_t)(b * NN + g) * AHS + hoff + c * 8];
    }
    a0 += bfpair(u.x); a1 += bfpair(u.y); a2 += bfpair(u.z); a3 += bfpair(u.w);
  };
  int e = ebeg;
  for (; e + 4 <= eend; e += 4) {
    unsigned o0 = eoff[e], o1 = eoff[e + 1], o2 = eoff[e + 2], o3 = eoff[e + 3];
    if (!((((o0 + 1) | (o1 + 1) | (o2 + 1) | (o3 + 1)) >> 16))) {
      uint4 u0 = *(const uint4*)(smemc + o0 + cb);
      uint4 u1 = *(const uint4*)(smemc + o1 + cb);
      uint4 u2 = *(const uint4*)(smemc + o2 + cb);
      uint4 u3 = *(const uint4*)(smemc + o3 + cb);
      a0 += bfpair(u0.x); a1 += bfpair(u0.y); a2 += bfpair(u0.z); a3 += bfpair(u0.w);
      a0 += bfpair(u1.x); a1 += bfpair(u1.y); a2 += bfpair(u1.z); a3 += bfpair(u1.w);
      a0 += bfpair(u2.x); a1 += bfpair(u2.y); a2 += bfpair(u2.z); a3 += bfpair(u2.w);
      a0 += bfpair(u3.x); a1 += bfpair(u3.y); a2 += bfpair(u3.z); a3 += bfpair(u3.w);
    } else {
      one(e); one(e + 1); one(e + 2); one(e + 3);
    }
  }
  for (; e < eend; ++e) one(e);
  // combine the two edge-halves (lanes tid^16 share leaf & column)
  a0[0] += __shfl_xor(a0[0], 16); a0[1] += __shfl_xor(a0[1], 16);
  a1[0] += __shfl_xor(a1[0], 16); a1[1] += __shfl_xor(a1[1], 16);
  a2[0] += __shfl_xor(a2[0], 16); a2[1] += __shfl_xor(a2[1], 16);
  a3[0] += __shfl_xor(a3[0], 16); a3[1] += __shfl_xor(a3[1], 16);
  if (!half) {
    float inv = 1.0f / (float)max(n, 1);
    unsigned short* aggl = (unsigned short*)(smemc + AGGL_OFF);
    __attribute__((aligned(16))) unsigned short o[8];
    o[0] = f2bf(a0[0] * inv); o[1] = f2bf(a0[1] * inv);
    o[2] = f2bf(a1[0] * inv); o[3] = f2bf(a1[1] * inv);
    o[4] = f2bf(a2[0] * inv); o[5] = f2bf(a2[1] * inv);
    o[6] = f2bf(a3[0] * inv); o[7] = f2bf(a3[1] * inv);
    *(uint4*)&aggl[leaf * CSTRIDE + c * 8] = *(uint4*)&o[0];
  }
}

// ---------------------------------------------------------------------------
// Finish agg for nodes 0..15 (tid<128); h at +hoff, closed-form deg.
__device__ __forceinline__ void ph_topfin(int b,
                                          const float* __restrict__ sroot,
                                          unsigned short* ah, int hoff) {
  int d = threadIdx.x;
  float S16[16], h16[16], Sv[16];
#pragma unroll
  for (int j = 0; j < 16; ++j) S16[j] = sroot[(size_t)(b * 16 + j) * DD + d];
#pragma unroll
  for (int j = 0; j < 16; ++j)
    h16[j] = bf2f(ah[(size_t)(b * NN + 16 + j) * AHS + hoff + d]);
#pragma unroll
  for (int k = 8; k < 16; ++k)
    Sv[k] = h16[2 * k - 16] + h16[2 * k - 15] + S16[2 * k - 16] + S16[2 * k - 15];
#pragma unroll
  for (int k = 7; k >= 1; --k)
    Sv[k] = bf2f(ah[(size_t)(b * NN + 2 * k) * AHS + hoff + d]) +
            bf2f(ah[(size_t)(b * NN + 2 * k + 1) * AHS + hoff + d]) +
            Sv[2 * k] + Sv[2 * k + 1];
#pragma unroll
  for (int k = 1; k < 16; ++k) {
    int dv = 31 - __clz(k);
    float inv = 1.0f / (float)((1 << (11 - dv)) - 2);
    ah[(size_t)(b * NN + k) * AHS + d] = f2bf(Sv[k] * inv);
  }
  ah[(size_t)(b * NN) * AHS + d] = f2bf(0.0f);
}

// ---------------------------------------------------------------------------
// 32-row leaf GEMM tile (contiguous rows at rowbase). agg A-operand (kc<4)
// comes from the aggl LDS buffer. Waves 8-15 inactive (barrier-only).
__device__ __forceinline__ void ph_gemm32(char* redc, const unsigned short* aggl,
                                          int rowbase, unsigned short* ah,
                                          const unsigned short* __restrict__ wfl,
                                          const float* __restrict__ bn,
                                          float* __restrict__ x, int hoff_in,
                                          const float* __restrict__ gamma,
                                          const float* __restrict__ beta,
                                          float* xc, int first_layer) {
  int wave = threadIdx.x >> 6, lane = threadIdx.x & 63;
  bool act = wave < 8;
  int mt = (wave & 7) >> 2, nq = wave & 3;
  int r0 = rowbase + mt * 16;
  int m = lane & 15, q = lane >> 4;
  floatx4 acc[2];
  acc[0] = (floatx4){0.f, 0.f, 0.f, 0.f};
  acc[1] = (floatx4){0.f, 0.f, 0.f, 0.f};
  if (act) {
    const unsigned short* arow = ah + (size_t)(r0 + m) * AHS + q * 8;
    const bf16x8* B = (const bf16x8*)wfl + lane;
#pragma unroll
    for (int kc = 0; kc < 8; ++kc) {
      bf16x8 a0;
      if (kc < 4)
        a0 = *(const bf16x8*)&aggl[(mt * 16 + m) * CSTRIDE + kc * 32 + q * 8];
      else
        a0 = *(const bf16x8*)(arow + hoff_in + (kc - 4) * 32);
#pragma unroll
      for (int ci = 0; ci < 2; ++ci) {
        bf16x8 bb = B[(kc * 8 + nq * 2 + ci) * 64];
        acc[ci] = __builtin_amdgcn_mfma_f32_16x16x32_bf16(a0, bb, acc[ci], 0, 0, 0);
      }
    }
  }
  if (first_layer) {
    float s1[4] = {0.f, 0.f, 0.f, 0.f}, s2[4] = {0.f, 0.f, 0.f, 0.f};
    if (act) {
#pragma unroll
      for (int ci = 0; ci < 2; ++ci) {
        int col = (nq * 2 + ci) * 16 + m;
        float bias = bn[col];
#pragma unroll
        for (int r = 0; r < 4; ++r) {
          int row = r0 + q * 4 + r;
          float v = x[(size_t)row * DD + col] + acc[ci][r] + bias;
          xc[ci * 4 + r] = v;
          s1[r] += v; s2[r] += v * v;
        }
      }
#pragma unroll
      for (int r = 0; r < 4; ++r) {
        s1[r] += __shfl_xor(s1[r], 1); s2[r] += __shfl_xor(s2[r], 1);
        s1[r] += __shfl_xor(s1[r], 2); s2[r] += __shfl_xor(s2[r], 2);
        s1[r] += __shfl_xor(s1[r], 4); s2[r] += __shfl_xor(s2[r], 4);
        s1[r] += __shfl_xor(s1[r], 8); s2[r] += __shfl_xor(s2[r], 8);
      }
    }
    float* red = (float*)redc;
    int rl = mt * 16 + q * 4;
    __syncthreads();
    if (act && m == 0) {
#pragma unroll
      for (int r = 0; r < 4; ++r) {
        red[(rl + r) * 4 + nq] = s1[r];
        red[128 + (rl + r) * 4 + nq] = s2[r];
      }
    }
    __syncthreads();
    if (act) {
      float mu[4], rv[4];
#pragma unroll
      for (int r = 0; r < 4; ++r) {
        float t1 = red[(rl + r) * 4] + red[(rl + r) * 4 + 1] +
                   red[(rl + r) * 4 + 2] + red[(rl + r) * 4 + 3];
        float t2 = red[128 + (rl + r) * 4] + red[128 + (rl + r) * 4 + 1] +
                   red[128 + (rl + r) * 4 + 2] + red[128 + (rl + r) * 4 + 3];
        mu[r] = t1 * (1.0f / 128.0f);
        float var = t2 * (1.0f / 128.0f) - mu[r] * mu[r];
        rv[r] = rsqrtf(var + 1e-5f);
      }
#pragma unroll
      for (int ci = 0; ci < 2; ++ci) {
        int col = (nq * 2 + ci) * 16 + m;
        float gm = gamma[col], bt = beta[col];
#pragma unroll
        for (int r = 0; r < 4; ++r) {
          int row = r0 + q * 4 + r;
          float hh = gelu((xc[ci * 4 + r] - mu[r]) * rv[r] * gm + bt);
          ah[(size_t)row * AHS + 256 + col] = f2bf(hh);
        }
      }
    }
  } else {
    if (act) {
#pragma unroll
      for (int ci = 0; ci < 2; ++ci) {
        int col = (nq * 2 + ci) * 16 + m;
        float bias = bn[col];
#pragma unroll
        for (int r = 0; r < 4; ++r) {
          int row = r0 + q * 4 + r;
          x[(size_t)row * DD + col] = xc[ci * 4 + r] + acc[ci][r] + bias;
        }
      }
    }
  }
}

// ---------------------------------------------------------------------------
// 32-row internal GEMM tile with SCATTERED rows: t = tbase+local, k = (t==63)?
// 1 : t+1, row = subtree-sb heap node. x0 preloaded in xc (no x read).
// Waves 8-15 inactive.
__device__ __forceinline__ void ph_gemm32s(char* redc, int b, int sb, int tbase,
                                           unsigned short* ah,
                                           const unsigned short* __restrict__ wfl,
                                           const float* __restrict__ bn,
                                           float* __restrict__ x, int hoff_in,
                                           const float* __restrict__ gamma,
                                           const float* __restrict__ beta,
                                           float* xc, int first_layer) {
  int wave = threadIdx.x >> 6, lane = threadIdx.x & 63;
  bool act = wave < 8;
  int mt = (wave & 7) >> 2, nq = wave & 3;
  int m = lane & 15, q = lane >> 4;
  int tA = tbase + mt * 16 + m;
  int kA = (tA == 63) ? 1 : tA + 1;
  int lvA = 31 - __clz(kA);
  int rowA = b * NN + (((16 + sb) << lvA) | (kA - (1 << lvA)));
  int rowO[4];
#pragma unroll
  for (int r = 0; r < 4; ++r) {
    int t = tbase + mt * 16 + q * 4 + r;
    int k = (t == 63) ? 1 : t + 1;
    int lv = 31 - __clz(k);
    rowO[r] = b * NN + (((16 + sb) << lv) | (k - (1 << lv)));
  }
  floatx4 acc[2];
  acc[0] = (floatx4){0.f, 0.f, 0.f, 0.f};
  acc[1] = (floatx4){0.f, 0.f, 0.f, 0.f};
  if (act) {
    const unsigned short* arow = ah + (size_t)rowA * AHS + q * 8;
    const bf16x8* B = (const bf16x8*)wfl + lane;
#pragma unroll
    for (int kc = 0; kc < 8; ++kc) {
      int koff = (kc < 4) ? kc * 32 : hoff_in + (kc - 4) * 32;
      bf16x8 a0 = *(const bf16x8*)(arow + koff);
#pragma unroll
      for (int ci = 0; ci < 2; ++ci) {
        bf16x8 bb = B[(kc * 8 + nq * 2 + ci) * 64];
        acc[ci] = __builtin_amdgcn_mfma_f32_16x16x32_bf16(a0, bb, acc[ci], 0, 0, 0);
      }
    }
  }
  if (first_layer) {
    float s1[4] = {0.f, 0.f, 0.f, 0.f}, s2[4] = {0.f, 0.f, 0.f, 0.f};
    if (act) {
#pragma unroll
      for (int ci = 0; ci < 2; ++ci) {
        int col = (nq * 2 + ci) * 16 + m;
        float bias = bn[col];
#pragma unroll
        for (int r = 0; r < 4; ++r) {
          float v = xc[ci * 4 + r] + acc[ci][r] + bias;
          xc[ci * 4 + r] = v;
          s1[r] += v; s2[r] += v * v;
        }
      }
#pragma unroll
      for (int r = 0; r < 4; ++r) {
        s1[r] += __shfl_xor(s1[r], 1); s2[r] += __shfl_xor(s2[r], 1);
        s1[r] += __shfl_xor(s1[r], 2); s2[r] += __shfl_xor(s2[r], 2);
        s1[r] += __shfl_xor(s1[r], 4); s2[r] += __shfl_xor(s2[r], 4);
        s1[r] += __shfl_xor(s1[r], 8); s2[r] += __shfl_xor(s2[r], 8);
      }
    }
    float* red = (float*)redc;
    int rl = mt * 16 + q * 4;
    __syncthreads();
    if (act && m == 0) {
#pragma unroll
      for (int r = 0; r < 4; ++r) {
        red[(rl + r) * 4 + nq] = s1[r];
        red[128 + (rl + r) * 4 + nq] = s2[r];
      }
    }
    __syncthreads();
    if (act) {
      float mu[4], rv[4];
#pragma unroll
      for (int r = 0; r < 4; ++r) {
        float t1 = red[(rl + r) * 4] + red[(rl + r) * 4 + 1] +
                   red[(rl + r) * 4 + 2] + red[(rl + r) * 4 + 3];
        float t2 = red[128 + (rl + r) * 4] + red[128 + (rl + r) * 4 + 1] +
                   red[128 + (rl + r) * 4 + 2] + red[128 + (rl + r) * 4 + 3];
        mu[r] = t1 * (1.0f / 128.0f);
        float var = t2 * (1.0f / 128.0f) - mu[r] * mu[r];
        rv[r] = rsqrtf(var + 1e-5f);
      }
#pragma unroll
      for (int ci = 0; ci < 2; ++ci) {
        int col = (nq * 2 + ci) * 16 + m;
        float gm = gamma[col], bt = beta[col];
#pragma unroll
        for (int r = 0; r < 4; ++r) {
          float hh = gelu((xc[ci * 4 + r] - mu[r]) * rv[r] * gm + bt);
          ah[(size_t)rowO[r] * AHS + 256 + col] = f2bf(hh);
        }
      }
    }
  } else {
    if (act) {
#pragma unroll
      for (int ci = 0; ci < 2; ++ci) {
        int col = (nq * 2 + ci) * 16 + m;
        float bias = bn[col];
#pragma unroll
        for (int r = 0; r < 4; ++r)
          x[(size_t)rowO[r] * DD + col] = xc[ci * 4 + r] + acc[ci][r] + bias;
      }
    }
  }
}

// ---------------------------------------------------------------------------
// 16-row top GEMM tile (rows 0..15 of batch b). Waves 0-7 = 8 col-tiles;
// waves 8-15 inactive.
__device__ __forceinline__ void ph_gemm16t(char* redc, int b,
                                           unsigned short* ah,
                                           const unsigned short* __restrict__ wfl,
                                           const float* __restrict__ bn,
                                           float* __restrict__ x, int hoff_in,
                                           const float* __restrict__ gamma,
                                           const float* __restrict__ beta,
                                           float* xc, int first_layer) {
  int ct = threadIdx.x >> 6, lane = threadIdx.x & 63;
  bool act = ct < 8;
  int m = lane & 15, q = lane >> 4;
  floatx4 acc = (floatx4){0.f, 0.f, 0.f, 0.f};
  int col = (ct & 7) * 16 + m;
  if (act) {
    const unsigned short* arow = ah + (size_t)(b * NN + m) * AHS + q * 8;
    const bf16x8* B = (const bf16x8*)wfl + lane;
#pragma unroll
    for (int kc = 0; kc < 8; ++kc) {
      int koff = (kc < 4) ? kc * 32 : hoff_in + (kc - 4) * 32;
      bf16x8 a0 = *(const bf16x8*)(arow + koff);
      bf16x8 bb = B[(kc * 8 + ct) * 64];
      acc = __builtin_amdgcn_mfma_f32_16x16x32_bf16(a0, bb, acc, 0, 0, 0);
    }
  }
  if (first_layer) {
    float s1[4] = {0.f, 0.f, 0.f, 0.f}, s2[4] = {0.f, 0.f, 0.f, 0.f};
    float bias = act ? bn[col] : 0.f;
    if (act) {
#pragma unroll
      for (int r = 0; r < 4; ++r) {
        float v = xc[r] + acc[r] + bias;
        xc[r] = v; s1[r] = v; s2[r] = v * v;
      }
#pragma unroll
      for (int r = 0; r < 4; ++r) {
        s1[r] += __shfl_xor(s1[r], 1); s2[r] += __shfl_xor(s2[r], 1);
        s1[r] += __shfl_xor(s1[r], 2); s2[r] += __shfl_xor(s2[r], 2);
        s1[r] += __shfl_xor(s1[r], 4); s2[r] += __shfl_xor(s2[r], 4);
        s1[r] += __shfl_xor(s1[r], 8); s2[r] += __shfl_xor(s2[r], 8);
      }
    }
    float* red = (float*)redc;
    __syncthreads();
    if (act && m == 0) {
#pragma unroll
      for (int r = 0; r < 4; ++r) {
        red[(q * 4 + r) * 8 + ct] = s1[r];
        red[128 + (q * 4 + r) * 8 + ct] = s2[r];
      }
    }
    __syncthreads();
    if (act) {
#pragma unroll
      for (int r = 0; r < 4; ++r) {
        float t1 = 0.f, t2 = 0.f;
#pragma unroll
        for (int j = 0; j < 8; ++j) {
          t1 += red[(q * 4 + r) * 8 + j];
          t2 += red[128 + (q * 4 + r) * 8 + j];
        }
        float mu = t1 * (1.0f / 128.0f);
        float var = t2 * (1.0f / 128.0f) - mu * mu;
        float rv = rsqrtf(var + 1e-5f);
        float hh = gelu((xc[r] - mu) * rv * gamma[col] + beta[col]);
        ah[(size_t)(b * NN + q * 4 + r) * AHS + 256 + col] = f2bf(hh);
      }
    }
  } else {
    if (act) {
      float bias = bn[col];
#pragma unroll
      for (int r = 0; r < 4; ++r)
        x[(size_t)(b * NN + q * 4 + r) * DD + col] = xc[r] + acc[r] + bias;
    }
  }
}

// ---------------------------------------------------------------------------
// Megakernel: 8 XCD-affine groups x 32 blocks (group = bid&7 = batch).
// gb 0-15: tree blocks. gb 16-23: CSR + eoff precompute (gb==16 also owns the
// top-node chain, gated on lvl4-ready flags). gb 24-27: weight repack.
__global__ __launch_bounds__(NT, 1) void k_mega(
    const float* __restrict__ elements, const float* __restrict__ ln_gamma,
    const float* __restrict__ ln_beta, const float* __restrict__ w_nei,
    const float* __restrict__ b_nei, const float* __restrict__ w_root,
    const int* __restrict__ srcv, const int* __restrict__ dstv, int E,
    float* __restrict__ x, int* s0a, int* s1a, float* lvl4, float* sroot,
    unsigned short* wf, unsigned short* ah, unsigned short* eoff, int* bar) {
  __shared__ __align__(16) char smem[65536];
  int bid = blockIdx.x, tid = threadIdx.x;
  int b = bid & 7, gb = bid >> 3;    // XCD-affine: batch = bid % 8
  int Eb = E >> 3;
  unsigned short* wfg = wf + (size_t)b * 65536;
  float xcl[8], xci[16], xct[4];

  // ---- P0 ----
  if (gb < 16) {
    ph_tree(smem, b, gb, elements, x, lvl4, ah, ln_gamma, ln_beta, sroot, xci, bar);
  } else if (gb < 24) {
    int base = b * Eb;
    for (int i = base + (gb - 16) * NT + tid; i < base + Eb; i += 8 * NT) {
      int dv = dstv[i];
      if (i == 0 || dstv[i - 1] != dv) s0a[dv] = i;
      if (i == base + Eb - 1 || dstv[i + 1] != dv) s1a[dv] = i + 1;
    }
    // precompute per-edge resolved cache byte-offsets for leaf-dst edges
    for (int i = base + (gb - 16) * NT + tid; i < base + Eb; i += 8 * NT) {
      int dl = dstv[i] - b * NN - 1024;
      unsigned short ov = 0xFFFFu;
      if (dl >= 0) {
        int jb2 = dl >> 5;
        int g = srcv[i] - b * NN;
        int lv = 31 - __clz(g);
        int acc2 = 0;
#pragma unroll
        for (int cd = 10; cd >= 1; --cd) {
          int lo_, wd_;
          win_cd(jb2, cd, lo_, wd_);
          if (cd == lv) {
            int idx = g - lo_;
            if ((unsigned)idx < (unsigned)wd_)
              ov = (unsigned short)((acc2 + idx) * (2 * CSTRIDE));
          }
          acc2 += wd_;
        }
      }
      eoff[i] = ov;
    }
    if (gb == 16) {
      // wait for all 16 lvl4 slices of this batch, then top-node x0 + h
      if (tid < 16) {
        while (!__hip_atomic_load(bar + 1536 + b * 64 + tid * 4, __ATOMIC_RELAXED,
                                  __HIP_MEMORY_SCOPE_AGENT))
          __builtin_amdgcn_s_sleep(1);
        __threadfence();
      }
      __syncthreads();
      ph_top(smem, b, lvl4, ah, ln_gamma, ln_beta);  // xs in LDS, h0..15 -> ah
      {                                              // stash xct from xs
        int wv = tid >> 6, ln = tid & 63, m_ = ln & 15, q_ = ln >> 4;
        if (wv < 8) {
          float (*xs)[DD] = (float(*)[DD])smem;
#pragma unroll
          for (int r = 0; r < 4; ++r) xct[r] = xs[q_ * 4 + r][wv * 16 + m_];
        }
      }
    }
  } else {
    int gi = (gb - 24) * NT + tid;   // 0..4095 frag units (gb 24-27)
    if (gi < 4096) {
      int lane = gi & 63, ct = (gi >> 6) & 7, kc = gi >> 9;
      int n = ct * 16 + (lane & 15);
      int k = kc * 32 + (lane >> 4) * 8;
      int kk = k & 127;
#pragma unroll
      for (int l = 0; l < 2; ++l) {
        const float* w = (k < 128) ? (w_nei + (size_t)l * DD * DD)
                                   : (w_root + (size_t)l * DD * DD);
        unsigned short* o = wfg + (size_t)l * 32768 + (size_t)gi * 8;
#pragma unroll
        for (int j = 0; j < 8; ++j) o[j] = f2bf(w[(size_t)(kk + j) * DD + n]);
      }
    }
  }
  gbarN(bar, 0);

  // ---- P1 (layer 0) ----
  if (gb == 16) {
    if (tid < 128) ph_topfin(b, sroot, ah, 128);
    __syncthreads();
    ph_gemm16t(smem + RED_OFF, b, ah, wfg, b_nei, x, 128,
               ln_gamma + DD, ln_beta + DD, xct, 1);
    __syncthreads();
  }
  ph_leafagg(smem, b, gb, srcv, s0a, s1a, eoff, ah, 128);
  __syncthreads();
  ph_gemm32(smem + RED_OFF, (const unsigned short*)(smem + AGGL_OFF),
            b * NN + 1024 + gb * 32, ah, wfg, b_nei, x, 128,
            ln_gamma + DD, ln_beta + DD, xcl, 1);
  if (gb < 16) {
    ph_gemm32s(smem + RED_OFF, b, gb, 0, ah, wfg, b_nei, x, 128,
               ln_gamma + DD, ln_beta + DD, xci, 1);
    ph_gemm32s(smem + RED_OFF, b, gb, 32, ah, wfg, b_nei, x, 128,
               ln_gamma + DD, ln_beta + DD, xci + 8, 1);
  }
  gbarN(bar, 1);

  // ---- P2 (layer 1): no group barrier; gb==16 waits on 16 sroot flags ----
  if (gb < 16) {
    ph_aggsub(smem, b, gb, ah, sroot);
    __syncthreads();
    if (tid == 0) {
      __threadfence();
      __hip_atomic_store(bar + 1024 + b * 64 + gb * 4, 1, __ATOMIC_RELAXED,
                         __HIP_MEMORY_SCOPE_AGENT);
    }
  }
  ph_leafagg(smem, b, gb, srcv, s0a, s1a, eoff, ah, 256);
  __syncthreads();
  ph_gemm32(smem + RED_OFF, (const unsigned short*)(smem + AGGL_OFF),
            b * NN + 1024 + gb * 32, ah, wfg + 32768, b_nei + DD,
            x, 256, ln_gamma, ln_beta, xcl, 0);
  if (gb < 16) {
    ph_gemm32s(smem + RED_OFF, b, gb, 0, ah, wfg + 32768, b_nei + DD, x, 256,
               ln_gamma, ln_beta, xci, 0);
    ph_gemm32s(smem + RED_OFF, b, gb, 32, ah, wfg + 32768, b_nei + DD, x, 256,
               ln_gamma, ln_beta, xci + 8, 0);
  } else if (gb == 16) {
    if (tid < 16) {
      while (!__hip_atomic_load(bar + 1024 + b * 64 + tid * 4, __ATOMIC_RELAXED,
                                __HIP_MEMORY_SCOPE_AGENT))
        __builtin_amdgcn_s_sleep(1);
      __threadfence();
    }
    __syncthreads();
    if (tid < 128) ph_topfin(b, sroot, ah, 256);
    __syncthreads();
    ph_gemm16t(smem + RED_OFF, b, ah, wfg + 32768, b_nei + DD, x, 256,
               ln_gamma, ln_beta, xct, 0);
  }
}

// ---------------------------------------------------------------------------
extern "C" void kernel_launch(void* const* d_in, const int* in_sizes, int n_in,
                              void* d_out, int out_size, void* d_ws, size_t ws_size,
                              hipStream_t stream) {
  const float* elements = (const float*)d_in[0];
  const float* ln_gamma = (const float*)d_in[1];
  const float* ln_beta  = (const float*)d_in[2];
  const float* w_nei    = (const float*)d_in[3];
  const float* b_nei    = (const float*)d_in[4];
  const float* w_root   = (const float*)d_in[5];
  const int*   edge     = (const int*)d_in[6];
  int E = in_sizes[6] / 2;
  const int* srcv = edge;
  const int* dstv = edge + E;
  float* x = (float*)d_out;

  char* ws = (char*)d_ws;
  int*            bar   = (int*)ws;                         // 8 KB used
  int*            s0    = (int*)(ws + 65536);               // 64 KB
  int*            s1    = (int*)(ws + 131072);              // 64 KB
  float*          lvl4  = (float*)(ws + 196608);            // 64 KB
  float*          sroot = (float*)(ws + 262144);            // 64 KB
  unsigned short* wf    = (unsigned short*)(ws + 327680);   // 1 MB (8 copies)
  unsigned short* ah    = (unsigned short*)(ws + 327680 + 1048576);  // 12.6 MB
  unsigned short* eoff  = (unsigned short*)(ws + 327680 + 1048576 + 12582912); // 2E B

  hipMemsetAsync(bar, 0, 8192, stream);
  k_mega<<<dim3(NB), dim3(NT), 0, stream>>>(
      elements, ln_gamma, ln_beta, w_nei, b_nei, w_root,
      srcv, dstv, E, x, s0, s1, lvl4, sroot, wf, ah, eoff, bar);
}

// Round 3
// 161.731 us; speedup vs baseline: 1.2346x; 1.0448x over previous
//
#include <hip/hip_runtime.h>
#include <hip/hip_bf16.h>

// Problem constants (fixed by the reference file)
#define LEAFN 1024
#define NN    2048            // nodes per batch incl. global node 0
#define BATCH 8
#define DD    128
#define ROWS  (BATCH*NN)      // 16384
#define AHS   384             // ah row stride: [agg(128) | hL0(128) | hL1(128)]
#define NB    256             // megakernel grid (1 block/CU)
#define NT    1024            // threads per block (16 waves)

// ln(10000)/32
#define LOG1E4_OVER_32 0.28782313662425575f

// leafagg LDS layout: cache (<=201 rows * 272B), leaf-agg buffer, 2 LN-red areas
#define SLACK 9               // proven window coverage: drift <= 9 both sides
#define CSTRIDE 136           // ushorts per cache row (272 B, odd multiple of 16B)
#define AGGL_OFF 54672        // 201 * 272
#define RED_OFF  63376        // AGGL_OFF + 32*272
#define RED2_OFF 64400        // RED_OFF + 1024 ; +1024 <= 65536

typedef __bf16 bf16x8 __attribute__((ext_vector_type(8)));
typedef float  floatx4 __attribute__((ext_vector_type(4)));
typedef float  floatx2 __attribute__((ext_vector_type(2)));

__device__ __forceinline__ float bf2f(unsigned short u) {
  return __uint_as_float(((unsigned)u) << 16);
}
__device__ __forceinline__ unsigned short f2bf(float f) {
  unsigned u = __float_as_uint(f);
  u += 0x7FFFu + ((u >> 16) & 1u);          // round-to-nearest-even
  return (unsigned short)(u >> 16);
}
__device__ __forceinline__ float gelu(float v) {
  return 0.5f * v * (1.0f + erff(v * 0.70710678118f));
}
__device__ __forceinline__ floatx2 bfpair(unsigned u) {
  floatx2 r;
  r[0] = __uint_as_float(u << 16);
  r[1] = __uint_as_float(u & 0xffff0000u);
  return r;
}

__device__ __forceinline__ float enc_val(int node, int d) {
  float hp, vp;
  if (node == 0) { hp = -0.5f; vp = -1.0f; }
  else {
    int v = 31 - __clz(node);
    hp = (float)(node - (1 << v));
    vp = (float)v;
  }
  float pos = (d < 64) ? hp : vp;
  int i = ((d < 64) ? d : (d - 64)) >> 1;
  float inv = __expf(-(float)i * LOG1E4_OVER_32);
  float ang = pos * inv;
  // |ang| <= 1023 rad = 163 rev, within v_sin range; error ~1e-5 << bf16 noise
  return (d & 1) ? __cosf(ang) : __sinf(ang);
}

// Cache window for block jb at level cd — MUST be identical in the eoff
// precompute and in ph_leafagg (single shared definition).
__device__ __forceinline__ void win_cd(int jb, int cd, int& lo_, int& wd_) {
  int g0 = 1024 + jb * 32, g1 = g0 + 31;
  int a0 = g0 >> (10 - cd), a1 = g1 >> (10 - cd);
  int l = a0 - SLACK, h = a1 + SLACK;
  int lvlo = 1 << cd, lvhi = (2 << cd) - 1;
  lo_ = l < lvlo ? lvlo : l;
  int hh = h > lvhi ? lvhi : h;
  int w = hh - lo_ + 1;
  wd_ = w < 0 ? 0 : w;
}

// ---------------------------------------------------------------------------
// Per-group barrier over 32 blocks. Group g = bid & 7.
__device__ __forceinline__ void gbarN(int* bar, int slot) {
  __syncthreads();
  if (threadIdx.x == 0) {
    int g = blockIdx.x & 7;
    int* base = bar + (slot * 8 + g) * 64;
    __threadfence();                           // release (L2 wb)
    if (__hip_atomic_fetch_add(base, 1, __ATOMIC_RELAXED,
                               __HIP_MEMORY_SCOPE_AGENT) == 31)
      __hip_atomic_store(base + 32, 1, __ATOMIC_RELAXED,
                         __HIP_MEMORY_SCOPE_AGENT);
    while (!__hip_atomic_load(base + 32, __ATOMIC_RELAXED,
                              __HIP_MEMORY_SCOPE_AGENT))
      __builtin_amdgcn_s_sleep(1);
    __threadfence();                           // acquire (L2 inv)
  }
  __syncthreads();
}

// ---------------------------------------------------------------------------
// Tree build + layer-0 LN/GELU + in-LDS subtree sums; stashes x0 of the t32
// internal-gemm tile rows into xci on WAVES 8-15 (which later run that tile).
// Writes x0 to global for leaf rows (k>=64) AND internal rows k<=32 (needed
// by the t0 tiles that now live on blocks 16-31).
__device__ __forceinline__ void ph_tree(char* smemc, int b, int s,
                                        const float* __restrict__ elements,
                                        float* __restrict__ x,
                                        float* __restrict__ lvl4,
                                        unsigned short* __restrict__ ah,
                                        const float* __restrict__ gamma,
                                        const float* __restrict__ beta,
                                        float* __restrict__ sroot,
                                        float* xci, int* bar) {
  float* sm = (float*)smemc;                  // 127*128 floats = 63.5 KB
  int tid = threadIdx.x;
  const float4* src = (const float4*)(elements + (size_t)(b * LEAFN + s * 64) * DD);
  for (int i = tid; i < 2048; i += NT) {
    int f = i * 4;
    int j = f >> 7, d = f & 127;
    *(float4*)&sm[(63 + j) * DD + d] = src[i];
  }
  __syncthreads();
  for (int lv = 5; lv >= 0; --lv) {
    int nodes = 1 << lv;
    for (int idx = tid; idx < nodes * DD; idx += NT) {
      int k = nodes + (idx >> 7);
      int d = idx & 127;
      sm[(k - 1) * DD + d] = 0.5f * (sm[(2 * k - 1) * DD + d] + sm[(2 * k) * DD + d]);
    }
    __syncthreads();
  }
  if (tid < DD) lvl4[(b * 16 + s) * DD + tid] = sm[tid];
  __syncthreads();
  if (tid == 0) {                             // release lvl4-ready flag
    __threadfence();
    __hip_atomic_store(bar + 1536 + b * 64 + s * 4, 1, __ATOMIC_RELAXED,
                       __HIP_MEMORY_SCOPE_AGENT);
  }
  // x = feat + enc; keep in sm; write global x for leaf rows AND k<=32 rows
  for (int idx = tid; idx < 127 * DD; idx += NT) {
    int k = (idx >> 7) + 1;
    int d = idx & 127;
    int lv = 31 - __clz(k);
    int g = ((16 + s) << lv) | (k - (1 << lv));
    float xv = sm[idx] + enc_val(g, d);
    if (k >= 64 || k <= 32) x[((size_t)(b * NN + g)) * DD + d] = xv;
    sm[idx] = xv;
  }
  __syncthreads();
  // stash x0 for this block's t32 gemm tile (32 rows, dup t=63->k=1).
  // Waves 8-15 stash (they run ph_gemm32s for this tile later).
  {
    int wave = tid >> 6, lane = tid & 63;
    if (wave >= 8) {
      int wl = wave & 7;
      int mt = wl >> 2, nq = wl & 3;
      int m = lane & 15, q = lane >> 4;
#pragma unroll
      for (int ci = 0; ci < 2; ++ci)
#pragma unroll
        for (int r = 0; r < 4; ++r) {
          int t = 32 + mt * 16 + q * 4 + r;
          int k = (t == 63) ? 1 : t + 1;
          int d = (nq * 2 + ci) * 16 + m;
          xci[ci * 4 + r] = sm[(k - 1) * DD + d];
        }
    }
  }
  __syncthreads();
  // LN + GELU: h -> ah(+128) AND h overwrites sm (fp32). float4 LDS access.
  {
    int sub = tid & 7, dp = sub * 16;
    for (int rr = tid >> 3; rr < 127; rr += NT / 8) {
      float* rowp = &sm[rr * DD + dp];
      float4 q0 = *(float4*)rowp;
      float4 q1 = *(float4*)(rowp + 4);
      float4 q2 = *(float4*)(rowp + 8);
      float4 q3 = *(float4*)(rowp + 12);
      float v[16] = {q0.x, q0.y, q0.z, q0.w, q1.x, q1.y, q1.z, q1.w,
                     q2.x, q2.y, q2.z, q2.w, q3.x, q3.y, q3.z, q3.w};
      float s1 = 0.f, s2 = 0.f;
#pragma unroll
      for (int j = 0; j < 16; ++j) { s1 += v[j]; s2 += v[j] * v[j]; }
      s1 += __shfl_xor(s1, 1); s2 += __shfl_xor(s2, 1);
      s1 += __shfl_xor(s1, 2); s2 += __shfl_xor(s2, 2);
      s1 += __shfl_xor(s1, 4); s2 += __shfl_xor(s2, 4);
      float mu = s1 * (1.0f / 128.0f);
      float var = s2 * (1.0f / 128.0f) - mu * mu;
      float rinv = rsqrtf(var + 1e-5f);
      int k = rr + 1, lv = 31 - __clz(k);
      int g = ((16 + s) << lv) | (k - (1 << lv));
      __attribute__((aligned(16))) unsigned short o[16];
      float hv[16];
#pragma unroll
      for (int j = 0; j < 16; ++j) {
        hv[j] = gelu((v[j] - mu) * rinv * gamma[dp + j] + beta[dp + j]);
        o[j] = f2bf(hv[j]);
      }
      *(float4*)rowp        = make_float4(hv[0], hv[1], hv[2], hv[3]);
      *(float4*)(rowp + 4)  = make_float4(hv[4], hv[5], hv[6], hv[7]);
      *(float4*)(rowp + 8)  = make_float4(hv[8], hv[9], hv[10], hv[11]);
      *(float4*)(rowp + 12) = make_float4(hv[12], hv[13], hv[14], hv[15]);
      unsigned short* dst = &ah[(size_t)(b * NN + g) * AHS + 128 + dp];
      *(uint4*)&dst[0] = *(uint4*)&o[0];
      *(uint4*)&dst[8] = *(uint4*)&o[8];
    }
  }
  __syncthreads();
  // subtree-sum pyramid in LDS; agg (closed-form deg) -> ah(+0)
  for (int lv = 5; lv >= 0; --lv) {
    int nk = 1 << lv;
    float inv = 1.0f / (float)((1 << (7 - lv)) - 2);
    for (int idx = tid; idx < nk * DD; idx += NT) {
      int k = nk + (idx >> 7);
      int d = idx & 127;
      float S = sm[(2 * k - 1) * DD + d] + sm[(2 * k) * DD + d];
      if (lv < 5) S += sm[(4 * k - 1) * DD + d] + sm[(4 * k + 1) * DD + d];
      sm[(2 * k - 1) * DD + d] = S;
      int g = ((16 + s) << lv) | (k - nk);
      ah[(size_t)(b * NN + g) * AHS + d] = f2bf(S * inv);
    }
    __syncthreads();
  }
  if (tid < DD) sroot[(size_t)(b * 16 + s) * DD + tid] = sm[DD + tid];
}

// ---------------------------------------------------------------------------
// Top nodes 0..15: x0 into LDS xs (no global write), layer-0 h -> ah.
__device__ __forceinline__ void ph_top(char* smemc, int b,
                                       const float* __restrict__ lvl4,
                                       unsigned short* __restrict__ ah,
                                       const float* __restrict__ gamma,
                                       const float* __restrict__ beta) {
  float (*xs)[DD] = (float(*)[DD])smemc;      // 8 KB
  int tid = threadIdx.x;
  if (tid < 128) {
    int d = tid;
    float v[16];
    for (int j = 0; j < 16; ++j) v[j] = lvl4[(b * 16 + j) * DD + d];
    for (int j = 0; j < 8; ++j) v[j] = 0.5f * (v[2 * j] + v[2 * j + 1]);
    for (int j = 0; j < 8; ++j) xs[8 + j][d] = v[j] + enc_val(8 + j, d);
    for (int j = 0; j < 4; ++j) v[j] = 0.5f * (v[2 * j] + v[2 * j + 1]);
    for (int j = 0; j < 4; ++j) xs[4 + j][d] = v[j] + enc_val(4 + j, d);
    for (int j = 0; j < 2; ++j) v[j] = 0.5f * (v[2 * j] + v[2 * j + 1]);
    for (int j = 0; j < 2; ++j) xs[2 + j][d] = v[j] + enc_val(2 + j, d);
    v[0] = 0.5f * (v[0] + v[1]);
    xs[1][d] = v[0] + enc_val(1, d);
    xs[0][d] = -1.0f + enc_val(0, d);
  }
  __syncthreads();
  if (tid < 128) {
    int rr = tid >> 3, sub = tid & 7, dp = sub * 16;
    float w[16], s1 = 0.f, s2 = 0.f;
#pragma unroll
    for (int j = 0; j < 16; ++j) { w[j] = xs[rr][dp + j]; s1 += w[j]; s2 += w[j] * w[j]; }
    s1 += __shfl_xor(s1, 1); s2 += __shfl_xor(s2, 1);
    s1 += __shfl_xor(s1, 2); s2 += __shfl_xor(s2, 2);
    s1 += __shfl_xor(s1, 4); s2 += __shfl_xor(s2, 4);
    float mu = s1 * (1.0f / 128.0f);
    float var = s2 * (1.0f / 128.0f) - mu * mu;
    float rinv = rsqrtf(var + 1e-5f);
    __attribute__((aligned(16))) unsigned short o[16];
#pragma unroll
    for (int j = 0; j < 16; ++j)
      o[j] = f2bf(gelu((w[j] - mu) * rinv * gamma[dp + j] + beta[dp + j]));
    unsigned short* dst = &ah[(size_t)(b * NN + rr) * AHS + 128 + dp];
    *(uint4*)&dst[0] = *(uint4*)&o[0];
    *(uint4*)&dst[8] = *(uint4*)&o[8];
  }
  __syncthreads();
}

// ---------------------------------------------------------------------------
// Subtree sums for L1: reads h' from ah(+256), agg -> ah(+0), sroot.
__device__ __forceinline__ void ph_aggsub(char* smemc, int b, int s,
                                          unsigned short* ah,
                                          float* __restrict__ sroot) {
  floatx4 (*S)[32] = (floatx4(*)[32])smemc;   // 32 KB
  int tid = threadIdx.x;
  for (int idx = tid; idx < 32 * 32; idx += NT) {
    int k = 32 + (idx >> 5), q = idx & 31;
    int c = (16 + s) * 64 + (2 * k - 64);
    size_t a0 = (size_t)(b * NN + c) * AHS + 256 + q * 4;
    ushort4 u0 = *(const ushort4*)&ah[a0];
    ushort4 u1 = *(const ushort4*)&ah[a0 + AHS];
    floatx4 v;
    v[0] = bf2f(u0.x) + bf2f(u1.x);
    v[1] = bf2f(u0.y) + bf2f(u1.y);
    v[2] = bf2f(u0.z) + bf2f(u1.z);
    v[3] = bf2f(u0.w) + bf2f(u1.w);
    S[k][q] = v;
    int g = (16 + s) * 32 + (k - 32);
    int r = b * NN + g;
    ushort4 o;
    o.x = f2bf(v[0] * 0.5f); o.y = f2bf(v[1] * 0.5f);
    o.z = f2bf(v[2] * 0.5f); o.w = f2bf(v[3] * 0.5f);
    *(ushort4*)&ah[(size_t)r * AHS + q * 4] = o;
  }
  __syncthreads();
  for (int lv = 4; lv >= 0; --lv) {
    int nk = 1 << lv;
    float inv = 1.0f / (float)((1 << (7 - lv)) - 2);
    for (int idx = tid; idx < nk * 32; idx += NT) {
      int k = nk + (idx >> 5), q = idx & 31;
      int c = ((16 + s) << (lv + 1)) | (2 * k - 2 * nk);
      size_t a0 = (size_t)(b * NN + c) * AHS + 256 + q * 4;
      ushort4 u0 = *(const ushort4*)&ah[a0];
      ushort4 u1 = *(const ushort4*)&ah[a0 + AHS];
      floatx4 sc0 = S[2 * k][q], sc1 = S[2 * k + 1][q];
      floatx4 v;
      v[0] = bf2f(u0.x) + bf2f(u1.x) + sc0[0] + sc1[0];
      v[1] = bf2f(u0.y) + bf2f(u1.y) + sc0[1] + sc1[1];
      v[2] = bf2f(u0.z) + bf2f(u1.z) + sc0[2] + sc1[2];
      v[3] = bf2f(u0.w) + bf2f(u1.w) + sc0[3] + sc1[3];
      S[k][q] = v;
      int g = ((16 + s) << lv) | (k - nk);
      int r = b * NN + g;
      ushort4 o;
      o.x = f2bf(v[0] * inv); o.y = f2bf(v[1] * inv);
      o.z = f2bf(v[2] * inv); o.w = f2bf(v[3] * inv);
      *(ushort4*)&ah[(size_t)r * AHS + q * 4] = o;
    }
    __syncthreads();
  }
  for (int q = tid; q < 32; q += NT)
    ((floatx4*)sroot)[(size_t)(b * 16 + s) * 32 + q] = S[1][q];
}

// ---------------------------------------------------------------------------
// Leaf-row gather: per-level LDS window cache; edge offsets precomputed in
// eoff[] (u16 cache byte offsets, 0xFFFF = global fallback). 32 threads per
// leaf: bit4 of tid selects which HALF of the edge range this thread walks;
// halves combined via shfl_xor(16). Result agg -> aggl LDS buffer.
__device__ __forceinline__ void ph_leafagg(char* smemc, int b, int jb,
                                           const int* __restrict__ srcv,
                                           const int* __restrict__ s0a,
                                           const int* __restrict__ s1a,
                                           const unsigned short* __restrict__ eoff,
                                           unsigned short* ah, int hoff) {
  unsigned short* cache = (unsigned short*)smemc;  // <= 54672 B
  int tid = threadIdx.x;
  int lo[11], wd[11], off[11];
  int acc_off = 0;
#pragma unroll
  for (int cd = 10; cd >= 1; --cd) {
    win_cd(jb, cd, lo[cd], wd[cd]);
    off[cd] = acc_off;
    acc_off += wd[cd];
  }
#pragma unroll
  for (int cd = 10; cd >= 1; --cd) {
    int w = wd[cd];
    for (int t = tid; t < w * 16; t += NT) {
      int row = t >> 4, seg = t & 15;
      *(uint4*)&cache[(off[cd] + row) * CSTRIDE + seg * 8] =
          *(const uint4*)&ah[(size_t)(b * NN + lo[cd] + row) * AHS + hoff + seg * 8];
    }
  }
  __syncthreads();

  int leaf = tid >> 5, half = (tid >> 4) & 1, c = tid & 15;
  int r = b * NN + 1024 + jb * 32 + leaf;
  int e0 = s0a[r], e1 = s1a[r];
  int n = e1 - e0;
  int mid = e0 + (n >> 1);
  int ebeg = half ? mid : e0;
  int eend = half ? e1 : mid;
  int cb = c * 16;
  floatx2 a0 = {0.f, 0.f}, a1 = {0.f, 0.f}, a2 = {0.f, 0.f}, a3 = {0.f, 0.f};
  auto one = [&](int ei) {
    unsigned o = eoff[ei];
    uint4 u;
    if (o != 0xFFFFu)
      u = *(const uint4*)(smemc + o + cb);
    else {
      int g = srcv[ei] - b * NN;
      u = *(const uint4*)&ah[(size_t)(b * NN + g) * AHS + hoff + c * 8];
    }
    a0 += bfpair(u.x); a1 += bfpair(u.y); a2 += bfpair(u.z); a3 += bfpair(u.w);
  };
  int e = ebeg;
  for (; e + 4 <= eend; e += 4) {
    unsigned o0 = eoff[e], o1 = eoff[e + 1], o2 = eoff[e + 2], o3 = eoff[e + 3];
    if (!((((o0 + 1) | (o1 + 1) | (o2 + 1) | (o3 + 1)) >> 16))) {
      uint4 u0 = *(const uint4*)(smemc + o0 + cb);
      uint4 u1 = *(const uint4*)(smemc + o1 + cb);
      uint4 u2 = *(const uint4*)(smemc + o2 + cb);
      uint4 u3 = *(const uint4*)(smemc + o3 + cb);
      a0 += bfpair(u0.x); a1 += bfpair(u0.y); a2 += bfpair(u0.z); a3 += bfpair(u0.w);
      a0 += bfpair(u1.x); a1 += bfpair(u1.y); a2 += bfpair(u1.z); a3 += bfpair(u1.w);
      a0 += bfpair(u2.x); a1 += bfpair(u2.y); a2 += bfpair(u2.z); a3 += bfpair(u2.w);
      a0 += bfpair(u3.x); a1 += bfpair(u3.y); a2 += bfpair(u3.z); a3 += bfpair(u3.w);
    } else {
      one(e); one(e + 1); one(e + 2); one(e + 3);
    }
  }
  for (; e < eend; ++e) one(e);
  // combine the two edge-halves (lanes tid^16 share leaf & column)
  a0[0] += __shfl_xor(a0[0], 16); a0[1] += __shfl_xor(a0[1], 16);
  a1[0] += __shfl_xor(a1[0], 16); a1[1] += __shfl_xor(a1[1], 16);
  a2[0] += __shfl_xor(a2[0], 16); a2[1] += __shfl_xor(a2[1], 16);
  a3[0] += __shfl_xor(a3[0], 16); a3[1] += __shfl_xor(a3[1], 16);
  if (!half) {
    float inv = 1.0f / (float)max(n, 1);
    unsigned short* aggl = (unsigned short*)(smemc + AGGL_OFF);
    __attribute__((aligned(16))) unsigned short o[8];
    o[0] = f2bf(a0[0] * inv); o[1] = f2bf(a0[1] * inv);
    o[2] = f2bf(a1[0] * inv); o[3] = f2bf(a1[1] * inv);
    o[4] = f2bf(a2[0] * inv); o[5] = f2bf(a2[1] * inv);
    o[6] = f2bf(a3[0] * inv); o[7] = f2bf(a3[1] * inv);
    *(uint4*)&aggl[leaf * CSTRIDE + c * 8] = *(uint4*)&o[0];
  }
}

// ---------------------------------------------------------------------------
// Finish agg for nodes 0..15 (tid<128); h at +hoff, closed-form deg.
__device__ __forceinline__ void ph_topfin(int b,
                                          const float* __restrict__ sroot,
                                          unsigned short* ah, int hoff) {
  int d = threadIdx.x;
  float S16[16], h16[16], Sv[16];
#pragma unroll
  for (int j = 0; j < 16; ++j) S16[j] = sroot[(size_t)(b * 16 + j) * DD + d];
#pragma unroll
  for (int j = 0; j < 16; ++j)
    h16[j] = bf2f(ah[(size_t)(b * NN + 16 + j) * AHS + hoff + d]);
#pragma unroll
  for (int k = 8; k < 16; ++k)
    Sv[k] = h16[2 * k - 16] + h16[2 * k - 15] + S16[2 * k - 16] + S16[2 * k - 15];
#pragma unroll
  for (int k = 7; k >= 1; --k)
    Sv[k] = bf2f(ah[(size_t)(b * NN + 2 * k) * AHS + hoff + d]) +
            bf2f(ah[(size_t)(b * NN + 2 * k + 1) * AHS + hoff + d]) +
            Sv[2 * k] + Sv[2 * k + 1];
#pragma unroll
  for (int k = 1; k < 16; ++k) {
    int dv = 31 - __clz(k);
    float inv = 1.0f / (float)((1 << (11 - dv)) - 2);
    ah[(size_t)(b * NN + k) * AHS + d] = f2bf(Sv[k] * inv);
  }
  ah[(size_t)(b * NN) * AHS + d] = f2bf(0.0f);
}

// ---------------------------------------------------------------------------
// 32-row leaf GEMM tile (contiguous rows at rowbase). agg A-operand (kc<4)
// from the aggl LDS buffer. Runs on waves 0-7 (concurrently with ph_gemm32s
// on waves 8-15); exactly 2 __syncthreads when first_layer, else 0.
__device__ __forceinline__ void ph_gemm32(char* redc, const unsigned short* aggl,
                                          int rowbase, unsigned short* ah,
                                          const unsigned short* __restrict__ wfl,
                                          const float* __restrict__ bn,
                                          float* __restrict__ x, int hoff_in,
                                          const float* __restrict__ gamma,
                                          const float* __restrict__ beta,
                                          float* xc, int first_layer) {
  int wave = threadIdx.x >> 6, lane = threadIdx.x & 63;
  bool act = wave < 8;
  int wl = wave & 7;
  int mt = wl >> 2, nq = wl & 3;
  int r0 = rowbase + mt * 16;
  int m = lane & 15, q = lane >> 4;
  floatx4 acc[2];
  acc[0] = (floatx4){0.f, 0.f, 0.f, 0.f};
  acc[1] = (floatx4){0.f, 0.f, 0.f, 0.f};
  if (act) {
    const unsigned short* arow = ah + (size_t)(r0 + m) * AHS + q * 8;
    const bf16x8* B = (const bf16x8*)wfl + lane;
#pragma unroll
    for (int kc = 0; kc < 8; ++kc) {
      bf16x8 a0;
      if (kc < 4)
        a0 = *(const bf16x8*)&aggl[(mt * 16 + m) * CSTRIDE + kc * 32 + q * 8];
      else
        a0 = *(const bf16x8*)(arow + hoff_in + (kc - 4) * 32);
#pragma unroll
      for (int ci = 0; ci < 2; ++ci) {
        bf16x8 bb = B[(kc * 8 + nq * 2 + ci) * 64];
        acc[ci] = __builtin_amdgcn_mfma_f32_16x16x32_bf16(a0, bb, acc[ci], 0, 0, 0);
      }
    }
  }
  if (first_layer) {
    float s1[4] = {0.f, 0.f, 0.f, 0.f}, s2[4] = {0.f, 0.f, 0.f, 0.f};
    if (act) {
#pragma unroll
      for (int ci = 0; ci < 2; ++ci) {
        int col = (nq * 2 + ci) * 16 + m;
        float bias = bn[col];
#pragma unroll
        for (int r = 0; r < 4; ++r) {
          int row = r0 + q * 4 + r;
          float v = x[(size_t)row * DD + col] + acc[ci][r] + bias;
          xc[ci * 4 + r] = v;
          s1[r] += v; s2[r] += v * v;
        }
      }
#pragma unroll
      for (int r = 0; r < 4; ++r) {
        s1[r] += __shfl_xor(s1[r], 1); s2[r] += __shfl_xor(s2[r], 1);
        s1[r] += __shfl_xor(s1[r], 2); s2[r] += __shfl_xor(s2[r], 2);
        s1[r] += __shfl_xor(s1[r], 4); s2[r] += __shfl_xor(s2[r], 4);
        s1[r] += __shfl_xor(s1[r], 8); s2[r] += __shfl_xor(s2[r], 8);
      }
    }
    float* red = (float*)redc;
    int rl = mt * 16 + q * 4;
    __syncthreads();
    if (act && m == 0) {
#pragma unroll
      for (int r = 0; r < 4; ++r) {
        red[(rl + r) * 4 + nq] = s1[r];
        red[128 + (rl + r) * 4 + nq] = s2[r];
      }
    }
    __syncthreads();
    if (act) {
      float mu[4], rv[4];
#pragma unroll
      for (int r = 0; r < 4; ++r) {
        float t1 = red[(rl + r) * 4] + red[(rl + r) * 4 + 1] +
                   red[(rl + r) * 4 + 2] + red[(rl + r) * 4 + 3];
        float t2 = red[128 + (rl + r) * 4] + red[128 + (rl + r) * 4 + 1] +
                   red[128 + (rl + r) * 4 + 2] + red[128 + (rl + r) * 4 + 3];
        mu[r] = t1 * (1.0f / 128.0f);
        float var = t2 * (1.0f / 128.0f) - mu[r] * mu[r];
        rv[r] = rsqrtf(var + 1e-5f);
      }
#pragma unroll
      for (int ci = 0; ci < 2; ++ci) {
        int col = (nq * 2 + ci) * 16 + m;
        float gm = gamma[col], bt = beta[col];
#pragma unroll
        for (int r = 0; r < 4; ++r) {
          int row = r0 + q * 4 + r;
          float hh = gelu((xc[ci * 4 + r] - mu[r]) * rv[r] * gm + bt);
          ah[(size_t)row * AHS + 256 + col] = f2bf(hh);
        }
      }
    }
  } else {
    if (act) {
#pragma unroll
      for (int ci = 0; ci < 2; ++ci) {
        int col = (nq * 2 + ci) * 16 + m;
        float bias = bn[col];
#pragma unroll
        for (int r = 0; r < 4; ++r) {
          int row = r0 + q * 4 + r;
          x[(size_t)row * DD + col] = xc[ci * 4 + r] + acc[ci][r] + bias;
        }
      }
    }
  }
}

// ---------------------------------------------------------------------------
// 32-row internal GEMM tile with SCATTERED rows: t = tbase+local, k = (t==63)?
// 1 : t+1, row = subtree-sb heap node. Runs on waves 8-15 (concurrent with
// ph_gemm32 on waves 0-7). first_layer residual: from gx (global x0) when
// gx != nullptr, else from xc registers. Exactly 2 __syncthreads when
// first_layer, else 0 (matches ph_gemm32's barrier count).
__device__ __forceinline__ void ph_gemm32s(char* redc, int b, int sb, int tbase,
                                           unsigned short* ah,
                                           const unsigned short* __restrict__ wfl,
                                           const float* __restrict__ bn,
                                           float* __restrict__ x, int hoff_in,
                                           const float* __restrict__ gamma,
                                           const float* __restrict__ beta,
                                           float* xc, int first_layer,
                                           const float* __restrict__ gx) {
  int wave = threadIdx.x >> 6, lane = threadIdx.x & 63;
  bool act = wave >= 8;
  int wl = wave & 7;
  int mt = wl >> 2, nq = wl & 3;
  int m = lane & 15, q = lane >> 4;
  int tA = tbase + mt * 16 + m;
  int kA = (tA == 63) ? 1 : tA + 1;
  int lvA = 31 - __clz(kA);
  int rowA = b * NN + (((16 + sb) << lvA) | (kA - (1 << lvA)));
  int rowO[4];
#pragma unroll
  for (int r = 0; r < 4; ++r) {
    int t = tbase + mt * 16 + q * 4 + r;
    int k = (t == 63) ? 1 : t + 1;
    int lv = 31 - __clz(k);
    rowO[r] = b * NN + (((16 + sb) << lv) | (k - (1 << lv)));
  }
  floatx4 acc[2];
  acc[0] = (floatx4){0.f, 0.f, 0.f, 0.f};
  acc[1] = (floatx4){0.f, 0.f, 0.f, 0.f};
  if (act) {
    const unsigned short* arow = ah + (size_t)rowA * AHS + q * 8;
    const bf16x8* B = (const bf16x8*)wfl + lane;
#pragma unroll
    for (int kc = 0; kc < 8; ++kc) {
      int koff = (kc < 4) ? kc * 32 : hoff_in + (kc - 4) * 32;
      bf16x8 a0 = *(const bf16x8*)(arow + koff);
#pragma unroll
      for (int ci = 0; ci < 2; ++ci) {
        bf16x8 bb = B[(kc * 8 + nq * 2 + ci) * 64];
        acc[ci] = __builtin_amdgcn_mfma_f32_16x16x32_bf16(a0, bb, acc[ci], 0, 0, 0);
      }
    }
  }
  if (first_layer) {
    float s1[4] = {0.f, 0.f, 0.f, 0.f}, s2[4] = {0.f, 0.f, 0.f, 0.f};
    if (act) {
#pragma unroll
      for (int ci = 0; ci < 2; ++ci) {
        int col = (nq * 2 + ci) * 16 + m;
        float bias = bn[col];
#pragma unroll
        for (int r = 0; r < 4; ++r) {
          float x0 = gx ? gx[(size_t)rowO[r] * DD + col] : xc[ci * 4 + r];
          float v = x0 + acc[ci][r] + bias;
          xc[ci * 4 + r] = v;
          s1[r] += v; s2[r] += v * v;
        }
      }
#pragma unroll
      for (int r = 0; r < 4; ++r) {
        s1[r] += __shfl_xor(s1[r], 1); s2[r] += __shfl_xor(s2[r], 1);
        s1[r] += __shfl_xor(s1[r], 2); s2[r] += __shfl_xor(s2[r], 2);
        s1[r] += __shfl_xor(s1[r], 4); s2[r] += __shfl_xor(s2[r], 4);
        s1[r] += __shfl_xor(s1[r], 8); s2[r] += __shfl_xor(s2[r], 8);
      }
    }
    float* red = (float*)redc;
    int rl = mt * 16 + q * 4;
    __syncthreads();
    if (act && m == 0) {
#pragma unroll
      for (int r = 0; r < 4; ++r) {
        red[(rl + r) * 4 + nq] = s1[r];
        red[128 + (rl + r) * 4 + nq] = s2[r];
      }
    }
    __syncthreads();
    if (act) {
      float mu[4], rv[4];
#pragma unroll
      for (int r = 0; r < 4; ++r) {
        float t1 = red[(rl + r) * 4] + red[(rl + r) * 4 + 1] +
                   red[(rl + r) * 4 + 2] + red[(rl + r) * 4 + 3];
        float t2 = red[128 + (rl + r) * 4] + red[128 + (rl + r) * 4 + 1] +
                   red[128 + (rl + r) * 4 + 2] + red[128 + (rl + r) * 4 + 3];
        mu[r] = t1 * (1.0f / 128.0f);
        float var = t2 * (1.0f / 128.0f) - mu[r] * mu[r];
        rv[r] = rsqrtf(var + 1e-5f);
      }
#pragma unroll
      for (int ci = 0; ci < 2; ++ci) {
        int col = (nq * 2 + ci) * 16 + m;
        float gm = gamma[col], bt = beta[col];
#pragma unroll
        for (int r = 0; r < 4; ++r) {
          float hh = gelu((xc[ci * 4 + r] - mu[r]) * rv[r] * gm + bt);
          ah[(size_t)rowO[r] * AHS + 256 + col] = f2bf(hh);
        }
      }
    }
  } else {
    if (act) {
#pragma unroll
      for (int ci = 0; ci < 2; ++ci) {
        int col = (nq * 2 + ci) * 16 + m;
        float bias = bn[col];
#pragma unroll
        for (int r = 0; r < 4; ++r)
          x[(size_t)rowO[r] * DD + col] = xc[ci * 4 + r] + acc[ci][r] + bias;
      }
    }
  }
}

// ---------------------------------------------------------------------------
// 16-row top GEMM tile (rows 0..15 of batch b). Waves 0-7 = 8 col-tiles;
// waves 8-15 inactive. Called by ALL waves (runs alone, not concurrent).
__device__ __forceinline__ void ph_gemm16t(char* redc, int b,
                                           unsigned short* ah,
                                           const unsigned short* __restrict__ wfl,
                                           const float* __restrict__ bn,
                                           float* __restrict__ x, int hoff_in,
                                           const float* __restrict__ gamma,
                                           const float* __restrict__ beta,
                                           float* xc, int first_layer) {
  int ct = threadIdx.x >> 6, lane = threadIdx.x & 63;
  bool act = ct < 8;
  int m = lane & 15, q = lane >> 4;
  floatx4 acc = (floatx4){0.f, 0.f, 0.f, 0.f};
  int col = (ct & 7) * 16 + m;
  if (act) {
    const unsigned short* arow = ah + (size_t)(b * NN + m) * AHS + q * 8;
    const bf16x8* B = (const bf16x8*)wfl + lane;
#pragma unroll
    for (int kc = 0; kc < 8; ++kc) {
      int koff = (kc < 4) ? kc * 32 : hoff_in + (kc - 4) * 32;
      bf16x8 a0 = *(const bf16x8*)(arow + koff);
      bf16x8 bb = B[(kc * 8 + ct) * 64];
      acc = __builtin_amdgcn_mfma_f32_16x16x32_bf16(a0, bb, acc, 0, 0, 0);
    }
  }
  if (first_layer) {
    float s1[4] = {0.f, 0.f, 0.f, 0.f}, s2[4] = {0.f, 0.f, 0.f, 0.f};
    float bias = act ? bn[col] : 0.f;
    if (act) {
#pragma unroll
      for (int r = 0; r < 4; ++r) {
        float v = xc[r] + acc[r] + bias;
        xc[r] = v; s1[r] = v; s2[r] = v * v;
      }
#pragma unroll
      for (int r = 0; r < 4; ++r) {
        s1[r] += __shfl_xor(s1[r], 1); s2[r] += __shfl_xor(s2[r], 1);
        s1[r] += __shfl_xor(s1[r], 2); s2[r] += __shfl_xor(s2[r], 2);
        s1[r] += __shfl_xor(s1[r], 4); s2[r] += __shfl_xor(s2[r], 4);
        s1[r] += __shfl_xor(s1[r], 8); s2[r] += __shfl_xor(s2[r], 8);
      }
    }
    float* red = (float*)redc;
    __syncthreads();
    if (act && m == 0) {
#pragma unroll
      for (int r = 0; r < 4; ++r) {
        red[(q * 4 + r) * 8 + ct] = s1[r];
        red[128 + (q * 4 + r) * 8 + ct] = s2[r];
      }
    }
    __syncthreads();
    if (act) {
#pragma unroll
      for (int r = 0; r < 4; ++r) {
        float t1 = 0.f, t2 = 0.f;
#pragma unroll
        for (int j = 0; j < 8; ++j) {
          t1 += red[(q * 4 + r) * 8 + j];
          t2 += red[128 + (q * 4 + r) * 8 + j];
        }
        float mu = t1 * (1.0f / 128.0f);
        float var = t2 * (1.0f / 128.0f) - mu * mu;
        float rv = rsqrtf(var + 1e-5f);
        float hh = gelu((xc[r] - mu) * rv * gamma[col] + beta[col]);
        ah[(size_t)(b * NN + q * 4 + r) * AHS + 256 + col] = f2bf(hh);
      }
    }
  } else {
    if (act) {
      float bias = bn[col];
#pragma unroll
      for (int r = 0; r < 4; ++r)
        x[(size_t)(b * NN + q * 4 + r) * DD + col] = xc[r] + acc[r] + bias;
    }
  }
}

// ---------------------------------------------------------------------------
// Megakernel: 8 XCD-affine groups x 32 blocks (group = bid&7 = batch).
// gb 0-15: tree + t32 tile. gb 16-31: t0 tile of subtree gb-16.
// gb 16-23: CSR + eoff precompute. gb 24-27: weight repack. gb 28: top chain.
// Every block: leafagg + concurrent [gemm32 (waves 0-7) || gemm32s (8-15)].
__global__ __launch_bounds__(NT, 1) void k_mega(
    const float* __restrict__ elements, const float* __restrict__ ln_gamma,
    const float* __restrict__ ln_beta, const float* __restrict__ w_nei,
    const float* __restrict__ b_nei, const float* __restrict__ w_root,
    const int* __restrict__ srcv, const int* __restrict__ dstv, int E,
    float* __restrict__ x, int* s0a, int* s1a, float* lvl4, float* sroot,
    unsigned short* wf, unsigned short* ah, unsigned short* eoff, int* bar) {
  __shared__ __align__(16) char smem[65536];
  int bid = blockIdx.x, tid = threadIdx.x;
  int b = bid & 7, gb = bid >> 3;    // XCD-affine: batch = bid % 8
  int Eb = E >> 3;
  unsigned short* wfg = wf + (size_t)b * 65536;
  float xcl[8], xci[8], xct[4];
  int wv = tid >> 6;

  // ---- P0 ----
  if (gb < 16) {
    ph_tree(smem, b, gb, elements, x, lvl4, ah, ln_gamma, ln_beta, sroot, xci, bar);
  } else if (gb < 24) {
    int base = b * Eb;
    for (int i = base + (gb - 16) * NT + tid; i < base + Eb; i += 8 * NT) {
      int dv = dstv[i];
      if (i == 0 || dstv[i - 1] != dv) s0a[dv] = i;
      if (i == base + Eb - 1 || dstv[i + 1] != dv) s1a[dv] = i + 1;
    }
    // precompute per-edge resolved cache byte-offsets for leaf-dst edges
    for (int i = base + (gb - 16) * NT + tid; i < base + Eb; i += 8 * NT) {
      int dl = dstv[i] - b * NN - 1024;
      unsigned short ov = 0xFFFFu;
      if (dl >= 0) {
        int jb2 = dl >> 5;
        int g = srcv[i] - b * NN;
        int lv = 31 - __clz(g);
        int acc2 = 0;
#pragma unroll
        for (int cd = 10; cd >= 1; --cd) {
          int lo_, wd_;
          win_cd(jb2, cd, lo_, wd_);
          if (cd == lv) {
            int idx = g - lo_;
            if ((unsigned)idx < (unsigned)wd_)
              ov = (unsigned short)((acc2 + idx) * (2 * CSTRIDE));
          }
          acc2 += wd_;
        }
      }
      eoff[i] = ov;
    }
  } else if (gb < 28) {
    int gi = (gb - 24) * NT + tid;   // 0..4095 frag units
    int lane = gi & 63, ct = (gi >> 6) & 7, kc = gi >> 9;
    int n = ct * 16 + (lane & 15);
    int k = kc * 32 + (lane >> 4) * 8;
    int kk = k & 127;
#pragma unroll
    for (int l = 0; l < 2; ++l) {
      const float* w = (k < 128) ? (w_nei + (size_t)l * DD * DD)
                                 : (w_root + (size_t)l * DD * DD);
      unsigned short* o = wfg + (size_t)l * 32768 + (size_t)gi * 8;
#pragma unroll
      for (int j = 0; j < 8; ++j) o[j] = f2bf(w[(size_t)(kk + j) * DD + n]);
    }
  } else if (gb == 28) {
    // wait for all 16 lvl4 slices of this batch, then top-node x0 + h
    if (tid < 16) {
      while (!__hip_atomic_load(bar + 1536 + b * 64 + tid * 4, __ATOMIC_RELAXED,
                                __HIP_MEMORY_SCOPE_AGENT))
        __builtin_amdgcn_s_sleep(1);
      __threadfence();
    }
    __syncthreads();
    ph_top(smem, b, lvl4, ah, ln_gamma, ln_beta);  // xs in LDS, h0..15 -> ah
    {                                              // stash xct from xs (waves 0-7)
      int ln = tid & 63, m_ = ln & 15, q_ = ln >> 4;
      if (wv < 8) {
        float (*xs)[DD] = (float(*)[DD])smem;
#pragma unroll
        for (int r = 0; r < 4; ++r) xct[r] = xs[q_ * 4 + r][wv * 16 + m_];
      }
    }
  }
  gbarN(bar, 0);

  // ---- P1 (layer 0) ----
  if (gb == 28) {
    if (tid < 128) ph_topfin(b, sroot, ah, 128);
    __syncthreads();
    ph_gemm16t(smem + RED_OFF, b, ah, wfg, b_nei, x, 128,
               ln_gamma + DD, ln_beta + DD, xct, 1);
    __syncthreads();
  }
  ph_leafagg(smem, b, gb, srcv, s0a, s1a, eoff, ah, 128);
  __syncthreads();
  if (wv < 8) {
    ph_gemm32(smem + RED_OFF, (const unsigned short*)(smem + AGGL_OFF),
              b * NN + 1024 + gb * 32, ah, wfg, b_nei, x, 128,
              ln_gamma + DD, ln_beta + DD, xcl, 1);
  } else if (gb < 16) {
    ph_gemm32s(smem + RED2_OFF, b, gb, 32, ah, wfg, b_nei, x, 128,
               ln_gamma + DD, ln_beta + DD, xci, 1, nullptr);
  } else {
    ph_gemm32s(smem + RED2_OFF, b, gb - 16, 0, ah, wfg, b_nei, x, 128,
               ln_gamma + DD, ln_beta + DD, xci, 1, x);
  }
  gbarN(bar, 1);

  // ---- P2 (layer 1): no group barrier; gb==28 waits on 16 sroot flags ----
  if (gb < 16) {
    ph_aggsub(smem, b, gb, ah, sroot);
    __syncthreads();
    if (tid == 0) {
      __threadfence();
      __hip_atomic_store(bar + 1024 + b * 64 + gb * 4, 1, __ATOMIC_RELAXED,
                         __HIP_MEMORY_SCOPE_AGENT);
    }
  }
  ph_leafagg(smem, b, gb, srcv, s0a, s1a, eoff, ah, 256);
  __syncthreads();
  if (wv < 8) {
    ph_gemm32(smem + RED_OFF, (const unsigned short*)(smem + AGGL_OFF),
              b * NN + 1024 + gb * 32, ah, wfg + 32768, b_nei + DD,
              x, 256, ln_gamma, ln_beta, xcl, 0);
  } else if (gb < 16) {
    ph_gemm32s(smem + RED2_OFF, b, gb, 32, ah, wfg + 32768, b_nei + DD, x, 256,
               ln_gamma, ln_beta, xci, 0, nullptr);
  } else {
    ph_gemm32s(smem + RED2_OFF, b, gb - 16, 0, ah, wfg + 32768, b_nei + DD, x, 256,
               ln_gamma, ln_beta, xci, 0, nullptr);
  }
  if (gb == 28) {
    if (tid < 16) {
      while (!__hip_atomic_load(bar + 1024 + b * 64 + tid * 4, __ATOMIC_RELAXED,
                                __HIP_MEMORY_SCOPE_AGENT))
        __builtin_amdgcn_s_sleep(1);
      __threadfence();
    }
    __syncthreads();
    if (tid < 128) ph_topfin(b, sroot, ah, 256);
    __syncthreads();
    ph_gemm16t(smem + RED_OFF, b, ah, wfg + 32768, b_nei + DD, x, 256,
               ln_gamma, ln_beta, xct, 0);
  }
}

// ---------------------------------------------------------------------------
extern "C" void kernel_launch(void* const* d_in, const int* in_sizes, int n_in,
                              void* d_out, int out_size, void* d_ws, size_t ws_size,
                              hipStream_t stream) {
  const float* elements = (const float*)d_in[0];
  const float* ln_gamma = (const float*)d_in[1];
  const float* ln_beta  = (const float*)d_in[2];
  const float* w_nei    = (const float*)d_in[3];
  const float* b_nei    = (const float*)d_in[4];
  const float* w_root   = (const float*)d_in[5];
  const int*   edge     = (const int*)d_in[6];
  int E = in_sizes[6] / 2;
  const int* srcv = edge;
  const int* dstv = edge + E;
  float* x = (float*)d_out;

  char* ws = (char*)d_ws;
  int*            bar   = (int*)ws;                         // 8 KB used
  int*            s0    = (int*)(ws + 65536);               // 64 KB
  int*            s1    = (int*)(ws + 131072);              // 64 KB
  float*          lvl4  = (float*)(ws + 196608);            // 64 KB
  float*          sroot = (float*)(ws + 262144);            // 64 KB
  unsigned short* wf    = (unsigned short*)(ws + 327680);   // 1 MB (8 copies)
  unsigned short* ah    = (unsigned short*)(ws + 327680 + 1048576);  // 12.6 MB
  unsigned short* eoff  = (unsigned short*)(ws + 327680 + 1048576 + 12582912); // 2E B

  hipMemsetAsync(bar, 0, 8192, stream);
  k_mega<<<dim3(NB), dim3(NT), 0, stream>>>(
      elements, ln_gamma, ln_beta, w_nei, b_nei, w_root,
      srcv, dstv, E, x, s0, s1, lvl4, sroot, wf, ah, eoff, bar);
}